// Round 13
// baseline (320.673 us; speedup 1.0000x reference)
//
#include <hip/hip_runtime.h>
#include <math.h>

#define N_OUT 32
#define D_OUT 32
#define N_IN 2048
#define D_IN 16
#define BATCH 64
#define J 1024           // N_OUT*D_OUT

typedef __attribute__((ext_vector_type(8))) short short8;   // 8 bf16 (4 VGPR)
typedef __attribute__((ext_vector_type(4))) float f32x4;    // MFMA C/D

// f32 -> bf16 RNE
__device__ __forceinline__ unsigned short f2bf(float f) {
  unsigned int x = __float_as_uint(f);
  return (unsigned short)((x + 0x7FFFu + ((x >> 16) & 1u)) >> 16);
}

// 16B-unit swizzle inside one n-tile (2048 units): XOR bit0 with bit3
__device__ __forceinline__ int wp(int u) { return u ^ ((u >> 3) & 1); }

__device__ __forceinline__ void pack_col(const float* wc, uint4& d0, uint4& d1) {
  d0.x = (unsigned)f2bf(wc[0])  | ((unsigned)f2bf(wc[1])  << 16);
  d0.y = (unsigned)f2bf(wc[2])  | ((unsigned)f2bf(wc[3])  << 16);
  d0.z = (unsigned)f2bf(wc[4])  | ((unsigned)f2bf(wc[5])  << 16);
  d0.w = (unsigned)f2bf(wc[6])  | ((unsigned)f2bf(wc[7])  << 16);
  d1.x = (unsigned)f2bf(wc[8])  | ((unsigned)f2bf(wc[9])  << 16);
  d1.y = (unsigned)f2bf(wc[10]) | ((unsigned)f2bf(wc[11]) << 16);
  d1.z = (unsigned)f2bf(wc[12]) | ((unsigned)f2bf(wc[13]) << 16);
  d1.w = (unsigned)f2bf(wc[14]) | ((unsigned)f2bf(wc[15]) << 16);
}

// ============ NEW pass0: one block per 8-n chunk, ALL 64 b ============
// Kills the 4x bq-redundant W reads (536->134 MB) and amortizes each barrier
// over 16 MFMAs. acc[bq][q] accumulated in-place via MFMA C operand.
// MODE 0: also emit Wbf/ubf. MODE 2: no emission.
template<int MODE>
__global__ __launch_bounds__(1024, 1)
void pass0_kernel(const float* __restrict__ uf, const float* __restrict__ Wf,
                  short* __restrict__ Wbf, short* __restrict__ ubf,
                  float* __restrict__ part)
{
  __shared__ uint4 Wt[2][2048];     // double-buffered W tile (2 x 32KB)
  const int t  = threadIdx.x;
  const int l  = t & 63;
  const int w  = t >> 6;            // wave 0..15
  const int cx = blockIdx.x;        // unique chunk of 8 n, grid 256
  const int n0 = cx * 8;
  const int bl = l & 15;
  const int h  = l >> 4;            // D rows 4h..4h+3
  const int hA = h & 1;             // k-half (i 0-7 / 8-15) for lanes < 32
  const bool ld = (l < 32);

  int aoff[4];
  #pragma unroll
  for (int q = 0; q < 4; ++q) aoff[q] = wp(2 * ((w*4+q) * 16 + bl) + hA);

  f32x4 acc[4][4];                  // [bq][q]
  #pragma unroll
  for (int bq = 0; bq < 4; ++bq)
    #pragma unroll
    for (int q = 0; q < 4; ++q) acc[bq][q] = f32x4{0.f, 0.f, 0.f, 0.f};

  // prologue: stage W[n0]
  {
    float wc[16];
    const float* wsrc = Wf + (size_t)n0 * (D_IN * J) + t;
    #pragma unroll
    for (int i = 0; i < 16; ++i) wc[i] = wsrc[i * J];
    __builtin_amdgcn_sched_barrier(0);
    uint4 d0, d1;
    pack_col(wc, d0, d1);
    Wt[0][wp(2 * t)] = d0;
    Wt[0][wp(2 * t + 1)] = d1;
    if (MODE == 0) {
      uint4* gdst = reinterpret_cast<uint4*>(Wbf + (size_t)n0 * (D_IN * J));
      gdst[wp(2 * t)] = d0;
      gdst[wp(2 * t + 1)] = d1;
    }
  }
  __syncthreads();

  for (int nn = 0; nn < 8; ++nn) {
    const int n = n0 + nn;
    const int cur = nn & 1, nxt = cur ^ 1;
    const bool more = (nn + 1 < 8);

    // 1. u loads FIRST (so waiting on them leaves the W prefetch in flight),
    //    then next-n W loads, then fence the scheduler.
    float4 ua[4], ub[4];
    if (ld) {
      #pragma unroll
      for (int bq = 0; bq < 4; ++bq) {
        const float* up = uf + ((size_t)(bq * 16 + bl) * N_IN + n) * D_IN + hA * 8;
        ua[bq] = *reinterpret_cast<const float4*>(up);
        ub[bq] = *reinterpret_cast<const float4*>(up + 4);
      }
    }
    float wc[16];
    if (more) {
      const float* wsrc = Wf + (size_t)(n + 1) * (D_IN * J) + t;
      #pragma unroll
      for (int i = 0; i < 16; ++i) wc[i] = wsrc[i * J];
    }
    __builtin_amdgcn_sched_barrier(0);

    // 2. pack u -> B frags (waits u loads only)
    short8 Bq[4];
    #pragma unroll
    for (int bq = 0; bq < 4; ++bq) Bq[bq] = short8{0,0,0,0,0,0,0,0};
    if (ld) {
      #pragma unroll
      for (int bq = 0; bq < 4; ++bq) {
        Bq[bq][0] = (short)f2bf(ua[bq].x); Bq[bq][1] = (short)f2bf(ua[bq].y);
        Bq[bq][2] = (short)f2bf(ua[bq].z); Bq[bq][3] = (short)f2bf(ua[bq].w);
        Bq[bq][4] = (short)f2bf(ub[bq].x); Bq[bq][5] = (short)f2bf(ub[bq].y);
        Bq[bq][6] = (short)f2bf(ub[bq].z); Bq[bq][7] = (short)f2bf(ub[bq].w);
      }
      if (MODE == 0 && w == 0) {
        #pragma unroll
        for (int bq = 0; bq < 4; ++bq)
          *reinterpret_cast<short8*>(ubf + ((size_t)(bq * 16 + bl) * N_IN + n) * D_IN + hA * 8) = Bq[bq];
      }
    }

    // 3. MFMA: A read once per q, accumulated into 4 bq accs in place
    const uint4* buf = Wt[cur];
    #pragma unroll
    for (int q = 0; q < 4; ++q) {
      short8 A = short8{0,0,0,0,0,0,0,0};
      if (ld) A = *reinterpret_cast<const short8*>(&buf[aoff[q]]);
      #pragma unroll
      for (int bq = 0; bq < 4; ++bq)
        acc[bq][q] = __builtin_amdgcn_mfma_f32_16x16x32_bf16(A, Bq[bq], acc[bq][q], 0, 0, 0);
    }

    // 4. write-late next W tile
    if (more) {
      uint4 d0, d1;
      pack_col(wc, d0, d1);
      Wt[nxt][wp(2 * t)] = d0;
      Wt[nxt][wp(2 * t + 1)] = d1;
      if (MODE == 0) {
        uint4* gdst = reinterpret_cast<uint4*>(Wbf + (size_t)(n + 1) * (D_IN * J));
        gdst[wp(2 * t)] = d0;
        gdst[wp(2 * t + 1)] = d1;
      }
    }
    __syncthreads();
  }

  // epilogue: part[cx][j][b], all 64 b
  #pragma unroll
  for (int bq = 0; bq < 4; ++bq)
    #pragma unroll
    for (int q = 0; q < 4; ++q) {
      int jbase = (w * 4 + q) * 16 + h * 4;
      #pragma unroll
      for (int r = 0; r < 4; ++r)
        part[((size_t)cx * J + jbase + r) * 64 + bq * 16 + bl] = acc[bq][q][r];
    }
}

// MODE 0: load W f32, convert in-kernel, AND write bf16 copies out (pass 0)
// MODE 1: reg-staged pre-converted Wbf/ubf, 2 n per barrier pair (passes 1,2)
// MODE 2: like MODE 0 without writeout (fallback when ws too small)
template<bool HAS_V, int MODE, int NCHUNK>
__global__ __launch_bounds__(1024, 1)
void pass_kernel(const float* __restrict__ uf, const float* __restrict__ Wf,
                 short* __restrict__ Wbf, short* __restrict__ ubf,
                 const float* __restrict__ vin, float* __restrict__ part)
{
  constexpr int NBUF = (MODE == 1) ? 4 : 2;
  __shared__ uint4 Wt[NBUF][2048];        // W tiles (32KB each)
  __shared__ float al[2][2][32][18];      // logits -> c, [parity][npair][o][b]

  const int t  = threadIdx.x;
  const int l  = t & 63;
  const int w  = t >> 6;            // wave 0..15
  const int bid = blockIdx.x;
  const int bq = (bid >> 3) & 3;                    // b quadrant (16 b)
  const int cx = (bid & 7) | ((bid >> 5) << 3);     // chunk (XCD-grouped)
  const int n0 = cx * NCHUNK;

  const int bl = l & 15;            // D col = b_local
  const int b  = bq * 16 + bl;      // global b
  const int h  = l >> 4;            // 0..3: D rows 4h..4h+3
  const int hA = h & 1;             // k-half (i 0-7 / 8-15) for lanes < 32
  const bool ld = (l < 32);

  f32x4 vf[4];
  if (HAS_V) {
    #pragma unroll
    for (int q = 0; q < 4; ++q)
      vf[q] = *reinterpret_cast<const f32x4*>(vin + (size_t)b * J + (w*4+q)*16 + h*4);
  }

  int aoff[4];
  #pragma unroll
  for (int q = 0; q < 4; ++q) aoff[q] = wp(2 * ((w*4+q) * 16 + bl) + hA);

  f32x4 acc[4];
  #pragma unroll
  for (int q = 0; q < 4; ++q) acc[q] = f32x4{0.f, 0.f, 0.f, 0.f};

  if constexpr (MODE == 1) {
    // ============ MODE 1: paired-n, quad-buffered ============
    constexpr int NS = NCHUNK / 2;
    short8 Ba = short8{0,0,0,0,0,0,0,0}, Bb = short8{0,0,0,0,0,0,0,0};
    {
      const uint4* srcA = reinterpret_cast<const uint4*>(Wbf + (size_t)n0 * (D_IN * J));
      Wt[0][t] = srcA[t];
      Wt[0][t + 1024] = srcA[t + 1024];
      const uint4* srcB = reinterpret_cast<const uint4*>(Wbf + (size_t)(n0 + 1) * (D_IN * J));
      Wt[1][t] = srcB[t];
      Wt[1][t + 1024] = srcB[t + 1024];
      if (ld) {
        Ba = *reinterpret_cast<const short8*>(ubf + ((size_t)b * N_IN + n0) * D_IN + hA * 8);
        Bb = *reinterpret_cast<const short8*>(ubf + ((size_t)b * N_IN + n0 + 1) * D_IN + hA * 8);
      }
    }
    __syncthreads();

    for (int ss = 0; ss < NS; ++ss) {
      const int na = n0 + 2 * ss;
      const int p = ss & 1;
      const int par = ss & 1;
      const bool more = (ss + 1 < NS);

      uint4 sa0, sa1, sb0, sb1;
      short8 Bna = short8{0,0,0,0,0,0,0,0}, Bnb = short8{0,0,0,0,0,0,0,0};
      if (more) {
        const uint4* srcA = reinterpret_cast<const uint4*>(Wbf + (size_t)(na + 2) * (D_IN * J));
        sa0 = srcA[t];
        sa1 = srcA[t + 1024];
        const uint4* srcB = reinterpret_cast<const uint4*>(Wbf + (size_t)(na + 3) * (D_IN * J));
        sb0 = srcB[t];
        sb1 = srcB[t + 1024];
        if (ld) {
          Bna = *reinterpret_cast<const short8*>(ubf + ((size_t)b * N_IN + na + 2) * D_IN + hA * 8);
          Bnb = *reinterpret_cast<const short8*>(ubf + ((size_t)b * N_IN + na + 3) * D_IN + hA * 8);
        }
        __builtin_amdgcn_sched_barrier(0);
      }

      f32x4 Ca[4], Cb[4];
      {
        const uint4* bufA = Wt[2 * p];
        const uint4* bufB = Wt[2 * p + 1];
        #pragma unroll
        for (int q = 0; q < 4; ++q) {
          short8 A = short8{0,0,0,0,0,0,0,0};
          if (ld) A = *reinterpret_cast<const short8*>(&bufA[aoff[q]]);
          f32x4 z = f32x4{0.f, 0.f, 0.f, 0.f};
          Ca[q] = __builtin_amdgcn_mfma_f32_16x16x32_bf16(A, Ba, z, 0, 0, 0);
        }
        #pragma unroll
        for (int q = 0; q < 4; ++q) {
          short8 A = short8{0,0,0,0,0,0,0,0};
          if (ld) A = *reinterpret_cast<const short8*>(&bufB[aoff[q]]);
          f32x4 z = f32x4{0.f, 0.f, 0.f, 0.f};
          Cb[q] = __builtin_amdgcn_mfma_f32_16x16x32_bf16(A, Bb, z, 0, 0, 0);
        }
      }

      {
        float apa[2] = {0.f, 0.f}, apb[2] = {0.f, 0.f};
        #pragma unroll
        for (int q = 0; q < 4; ++q) {
          apa[q >> 1] += Ca[q][0]*vf[q][0] + Ca[q][1]*vf[q][1] + Ca[q][2]*vf[q][2] + Ca[q][3]*vf[q][3];
          apb[q >> 1] += Cb[q][0]*vf[q][0] + Cb[q][1]*vf[q][1] + Cb[q][2]*vf[q][2] + Cb[q][3]*vf[q][3];
        }
        #pragma unroll
        for (int p2 = 0; p2 < 2; ++p2) {
          float sa = apa[p2], sb = apb[p2];
          sa += __shfl_xor(sa, 16);
          sa += __shfl_xor(sa, 32);
          sb += __shfl_xor(sb, 16);
          sb += __shfl_xor(sb, 32);
          if (l < 16) {
            al[par][0][w * 2 + p2][l] = sa;
            al[par][1][w * 2 + p2][l] = sb;
          }
        }
      }

      if (more) {
        Wt[2 * (1 - p)][t] = sa0;
        Wt[2 * (1 - p)][t + 1024] = sa1;
        Wt[2 * (1 - p) + 1][t] = sb0;
        Wt[2 * (1 - p) + 1][t + 1024] = sb1;
      }

      __syncthreads();   // (B) logits staged
      {
        int npair = t >> 9, sb2 = (t >> 5) & 15, so = t & 31;
        float x = al[par][npair][so][sb2];
        float m = x;
        #pragma unroll
        for (int k = 1; k < 32; k <<= 1) m = fmaxf(m, __shfl_xor(m, k));
        float e = __expf(x - m);
        float sm = e;
        #pragma unroll
        for (int k = 1; k < 32; k <<= 1) sm += __shfl_xor(sm, k);
        al[par][npair][so][sb2] = e / sm;
      }
      __syncthreads();   // (C) c ready
      #pragma unroll
      for (int q = 0; q < 4; ++q) {
        float ca = al[par][0][(w * 4 + q) >> 1][bl];
        float cb = al[par][1][(w * 4 + q) >> 1][bl];
        acc[q] += Ca[q] * ca + Cb[q] * cb;
      }
      Ba = Bna;
      Bb = Bnb;
    }
  } else {
    // ============ MODE 0/2: f32 load + convert, MLP-forced ============
    const bool wq = (MODE == 0) && ((t >> 8) == bq);
    const bool uq = (MODE == 0) && (w == 0) && ld;

    short8 Bcur = short8{0,0,0,0,0,0,0,0};
    {
      float wc[16];
      const float* wsrc = Wf + (size_t)n0 * (D_IN * J) + t;
      #pragma unroll
      for (int i = 0; i < 16; ++i) wc[i] = wsrc[i * J];
      float4 a4 = {0,0,0,0}, b4 = {0,0,0,0};
      if (ld) {
        const float* up = uf + ((size_t)b * N_IN + n0) * D_IN + hA * 8;
        a4 = *reinterpret_cast<const float4*>(up);
        b4 = *reinterpret_cast<const float4*>(up + 4);
      }
      __builtin_amdgcn_sched_barrier(0);
      uint4 d0, d1;
      pack_col(wc, d0, d1);
      Wt[0][wp(2 * t)] = d0;
      Wt[0][wp(2 * t + 1)] = d1;
      if (wq) {
        uint4* gdst = reinterpret_cast<uint4*>(Wbf + (size_t)n0 * (D_IN * J));
        gdst[wp(2 * t)] = d0;
        gdst[wp(2 * t + 1)] = d1;
      }
      if (ld) {
        Bcur[0] = (short)f2bf(a4.x); Bcur[1] = (short)f2bf(a4.y);
        Bcur[2] = (short)f2bf(a4.z); Bcur[3] = (short)f2bf(a4.w);
        Bcur[4] = (short)f2bf(b4.x); Bcur[5] = (short)f2bf(b4.y);
        Bcur[6] = (short)f2bf(b4.z); Bcur[7] = (short)f2bf(b4.w);
        if (uq)
          *reinterpret_cast<short8*>(ubf + ((size_t)b * N_IN + n0) * D_IN + hA * 8) = Bcur;
      }
    }
    __syncthreads();

    for (int nn = 0; nn < NCHUNK; ++nn) {
      const int n = n0 + nn;
      const int cur = nn & 1, nxt = cur ^ 1, par = nn & 1;
      const bool more = (nn + 1 < NCHUNK);

      float wc[16];
      float4 a4 = {0,0,0,0}, b4 = {0,0,0,0};
      if (more) {
        const float* wsrc = Wf + (size_t)(n + 1) * (D_IN * J) + t;
        #pragma unroll
        for (int i = 0; i < 16; ++i) wc[i] = wsrc[i * J];
        if (ld) {
          const float* up = uf + ((size_t)b * N_IN + n + 1) * D_IN + hA * 8;
          a4 = *reinterpret_cast<const float4*>(up);
          b4 = *reinterpret_cast<const float4*>(up + 4);
        }
        __builtin_amdgcn_sched_barrier(0);
      }

      f32x4 C[4];
      const uint4* buf = Wt[cur];
      #pragma unroll
      for (int q = 0; q < 4; ++q) {
        short8 A = short8{0,0,0,0,0,0,0,0};
        if (ld) A = *reinterpret_cast<const short8*>(&buf[aoff[q]]);
        f32x4 z = f32x4{0.f, 0.f, 0.f, 0.f};
        C[q] = __builtin_amdgcn_mfma_f32_16x16x32_bf16(A, Bcur, z, 0, 0, 0);
      }

      short8 Bn = short8{0,0,0,0,0,0,0,0};
      if (more && ld) {
        Bn[0] = (short)f2bf(a4.x); Bn[1] = (short)f2bf(a4.y);
        Bn[2] = (short)f2bf(a4.z); Bn[3] = (short)f2bf(a4.w);
        Bn[4] = (short)f2bf(b4.x); Bn[5] = (short)f2bf(b4.y);
        Bn[6] = (short)f2bf(b4.z); Bn[7] = (short)f2bf(b4.w);
      }

      if (HAS_V) {
        float ap[2] = {0.f, 0.f};
        #pragma unroll
        for (int q = 0; q < 4; ++q) {
          float s = C[q][0]*vf[q][0] + C[q][1]*vf[q][1] + C[q][2]*vf[q][2] + C[q][3]*vf[q][3];
          ap[q >> 1] += s;
        }
        #pragma unroll
        for (int p = 0; p < 2; ++p) {
          float s = ap[p];
          s += __shfl_xor(s, 16);
          s += __shfl_xor(s, 32);
          if (l < 16) al[par][0][w * 2 + p][l] = s;
        }
        if (more) {
          uint4 d0, d1;
          pack_col(wc, d0, d1);
          Wt[nxt][wp(2 * t)] = d0;
          Wt[nxt][wp(2 * t + 1)] = d1;
          if (wq) {
            uint4* gdst = reinterpret_cast<uint4*>(Wbf + (size_t)(n + 1) * (D_IN * J));
            gdst[wp(2 * t)] = d0;
            gdst[wp(2 * t + 1)] = d1;
          }
          if (ld && uq)
            *reinterpret_cast<short8*>(ubf + ((size_t)b * N_IN + n + 1) * D_IN + hA * 8) = Bn;
        }
        __syncthreads();   // (B)
        if (t < 512) {
          int sb = t >> 5, so = t & 31;
          float x = al[par][0][so][sb];
          float m = x;
          #pragma unroll
          for (int k = 1; k < 32; k <<= 1) m = fmaxf(m, __shfl_xor(m, k));
          float e = __expf(x - m);
          float sm = e;
          #pragma unroll
          for (int k = 1; k < 32; k <<= 1) sm += __shfl_xor(sm, k);
          al[par][0][so][sb] = e / sm;
        }
        __syncthreads();   // (C)
        #pragma unroll
        for (int q = 0; q < 4; ++q) {
          float c = al[par][0][(w * 4 + q) >> 1][bl];
          acc[q] += C[q] * c;
        }
      } else {
        #pragma unroll
        for (int q = 0; q < 4; ++q) acc[q] += C[q];
        if (more) {
          uint4 d0, d1;
          pack_col(wc, d0, d1);
          Wt[nxt][wp(2 * t)] = d0;
          Wt[nxt][wp(2 * t + 1)] = d1;
          if (wq) {
            uint4* gdst = reinterpret_cast<uint4*>(Wbf + (size_t)(n + 1) * (D_IN * J));
            gdst[wp(2 * t)] = d0;
            gdst[wp(2 * t + 1)] = d1;
          }
          if (ld && uq)
            *reinterpret_cast<short8*>(ubf + ((size_t)b * N_IN + n + 1) * D_IN + hA * 8) = Bn;
        }
        __syncthreads();
      }
      Bcur = Bn;
    }
  }

  // epilogue: part[cx][j][b]
  #pragma unroll
  for (int q = 0; q < 4; ++q) {
    int jbase = (w * 4 + q) * 16 + h * 4;
    #pragma unroll
    for (int r = 0; r < 4; ++r)
      part[((size_t)cx * J + jbase + r) * 64 + b] = acc[q][r];
  }
}

// Fused chunk-reduce + squash. grid = 128 (o x b-quadrant), 1024 threads.
template<int NC>
__global__ __launch_bounds__(1024)
void rsq_kernel(const float* __restrict__ part, const float* __restrict__ addv,
                float* __restrict__ out, float prescale)
{
  __shared__ float ps[2][32][17];
  __shared__ float vl[32][17];
  __shared__ float scl[16];
  const int o  = blockIdx.x >> 2;
  const int bq = blockIdx.x & 3;
  const int t  = threadIdx.x;
  {
    const int bb = t & 15;
    const int kk = (t >> 4) & 31;
    const int ch = t >> 9;         // 0/1
    const float* p = part + (size_t)(o * 32 + kk) * 64 + bq * 16 + bb;
    float s = 0.f;
    #pragma unroll 8
    for (int c = ch * (NC / 2); c < (ch + 1) * (NC / 2); ++c)
      s += p[(size_t)c * (J * 64)];
    ps[ch][kk][bb] = s;
  }
  __syncthreads();
  if (t < 512) {
    int kk = t >> 4, bb = t & 15;
    vl[kk][bb] = (ps[0][kk][bb] + ps[1][kk][bb]) * prescale;
  }
  __syncthreads();
  if (t < 16) {
    float n2 = 0.f;
    #pragma unroll
    for (int k = 0; k < 32; ++k) { float x = vl[k][t]; n2 += x * x; }
    scl[t] = sqrtf(n2) / (1.f + n2);
  }
  __syncthreads();
  if (t < 512) {
    int bb = t >> 5, kk = t & 31;
    int idx = (bq * 16 + bb) * J + o * 32 + kk;
    float val = scl[bb] * vl[kk][bb];
    if (addv) val += addv[idx];
    out[idx] = val;
  }
}

extern "C" void kernel_launch(void* const* d_in, const int* in_sizes, int n_in,
                              void* d_out, int out_size, void* d_ws, size_t ws_size,
                              hipStream_t stream)
{
  const float* u = (const float*)d_in[0];
  const float* W = (const float*)d_in[1];
  float* out = (float*)d_out;
  char* ws = (char*)d_ws;

  const size_t WBF_B = (size_t)N_IN * D_IN * J * 2;        // 64 MB
  const size_t UBF_B = (size_t)BATCH * N_IN * D_IN * 2;    // 4 MB
  const size_t SMALL = 2ull * BATCH * J * 4;               // v0+vs
  const size_t PART256 = (size_t)256 * J * 64 * 4;         // 67.1 MB
  const size_t PART64  = (size_t)64 * J * 64 * 4;          // 16.7 MB

  if (ws_size >= WBF_B + UBF_B + PART256 + SMALL) {
    // NEW: pass0 with unique-chunk, all-64-b blocks (W read 1x, not 4x)
    short* Wbf = (short*)ws;
    short* ubf = (short*)(ws + WBF_B);
    float* part = (float*)(ws + WBF_B + UBF_B);
    float* v0 = part + (size_t)256 * J * 64;
    float* vs = v0 + BATCH * J;
    pass0_kernel<0><<<256, 1024, 0, stream>>>(u, W, Wbf, ubf, part);
    rsq_kernel<256><<<128, 1024, 0, stream>>>(part, nullptr, v0, 1.f / 32.f);
    pass_kernel<true, 1, 32><<<256, 1024, 0, stream>>>(u, W, Wbf, ubf, v0, part);
    rsq_kernel<64><<<128, 1024, 0, stream>>>(part, v0, vs, 1.f);
    pass_kernel<true, 1, 32><<<256, 1024, 0, stream>>>(u, W, Wbf, ubf, vs, part);
    rsq_kernel<64><<<128, 1024, 0, stream>>>(part, nullptr, out, 1.f);
  } else if (ws_size >= WBF_B + UBF_B + PART64 + SMALL) {
    // round-12 proven path
    short* Wbf = (short*)ws;
    short* ubf = (short*)(ws + WBF_B);
    float* part = (float*)(ws + WBF_B + UBF_B);
    float* v0 = part + (size_t)64 * J * 64;
    float* vs = v0 + BATCH * J;
    pass_kernel<false, 0, 32><<<256, 1024, 0, stream>>>(u, W, Wbf, ubf, nullptr, part);
    rsq_kernel<64><<<128, 1024, 0, stream>>>(part, nullptr, v0, 1.f / 32.f);
    pass_kernel<true, 1, 32><<<256, 1024, 0, stream>>>(u, W, Wbf, ubf, v0, part);
    rsq_kernel<64><<<128, 1024, 0, stream>>>(part, v0, vs, 1.f);
    pass_kernel<true, 1, 32><<<256, 1024, 0, stream>>>(u, W, Wbf, ubf, vs, part);
    rsq_kernel<64><<<128, 1024, 0, stream>>>(part, nullptr, out, 1.f);
  } else if (ws_size >= PART64 + SMALL) {
    float* part = (float*)ws;
    float* v0 = part + (size_t)64 * J * 64;
    float* vs = v0 + BATCH * J;
    pass_kernel<false, 2, 32><<<256, 1024, 0, stream>>>(u, W, nullptr, nullptr, nullptr, part);
    rsq_kernel<64><<<128, 1024, 0, stream>>>(part, nullptr, v0, 1.f / 32.f);
    pass_kernel<true, 2, 32><<<256, 1024, 0, stream>>>(u, W, nullptr, nullptr, v0, part);
    rsq_kernel<64><<<128, 1024, 0, stream>>>(part, v0, vs, 1.f);
    pass_kernel<true, 2, 32><<<256, 1024, 0, stream>>>(u, W, nullptr, nullptr, vs, part);
    rsq_kernel<64><<<128, 1024, 0, stream>>>(part, nullptr, out, 1.f);
  } else {
    float* part = (float*)ws;
    float* v0 = part + (size_t)16 * J * 64;
    float* vs = v0 + BATCH * J;
    pass_kernel<false, 2, 128><<<64, 1024, 0, stream>>>(u, W, nullptr, nullptr, nullptr, part);
    rsq_kernel<16><<<128, 1024, 0, stream>>>(part, nullptr, v0, 1.f / 32.f);
    pass_kernel<true, 2, 128><<<64, 1024, 0, stream>>>(u, W, nullptr, nullptr, v0, part);
    rsq_kernel<16><<<128, 1024, 0, stream>>>(part, v0, vs, 1.f);
    pass_kernel<true, 2, 128><<<64, 1024, 0, stream>>>(u, W, nullptr, nullptr, vs, part);
    rsq_kernel<16><<<128, 1024, 0, stream>>>(part, nullptr, out, 1.f);
  }
}

// Round 14
// 252.153 us; speedup vs baseline: 1.2717x; 1.2717x over previous
//
#include <hip/hip_runtime.h>
#include <math.h>

#define N_OUT 32
#define D_OUT 32
#define N_IN 2048
#define D_IN 16
#define BATCH 64
#define J 1024           // N_OUT*D_OUT

typedef __attribute__((ext_vector_type(8))) short short8;   // 8 bf16 (4 VGPR)
typedef __attribute__((ext_vector_type(4))) float f32x4;    // MFMA C/D

// f32 -> bf16 RNE
__device__ __forceinline__ unsigned short f2bf(float f) {
  unsigned int x = __float_as_uint(f);
  return (unsigned short)((x + 0x7FFFu + ((x >> 16) & 1u)) >> 16);
}

// 16B-unit swizzle inside one n-tile (2048 units): XOR bit0 with bit3
__device__ __forceinline__ int wp(int u) { return u ^ ((u >> 3) & 1); }

__device__ __forceinline__ void pack_col(const float* wc, uint4& d0, uint4& d1) {
  d0.x = (unsigned)f2bf(wc[0])  | ((unsigned)f2bf(wc[1])  << 16);
  d0.y = (unsigned)f2bf(wc[2])  | ((unsigned)f2bf(wc[3])  << 16);
  d0.z = (unsigned)f2bf(wc[4])  | ((unsigned)f2bf(wc[5])  << 16);
  d0.w = (unsigned)f2bf(wc[6])  | ((unsigned)f2bf(wc[7])  << 16);
  d1.x = (unsigned)f2bf(wc[8])  | ((unsigned)f2bf(wc[9])  << 16);
  d1.y = (unsigned)f2bf(wc[10]) | ((unsigned)f2bf(wc[11]) << 16);
  d1.z = (unsigned)f2bf(wc[12]) | ((unsigned)f2bf(wc[13]) << 16);
  d1.w = (unsigned)f2bf(wc[14]) | ((unsigned)f2bf(wc[15]) << 16);
}

// ============ pass1: routing passes, 512-thread blocks, 2 blocks/CU ============
// 8 waves x 8 j-tiles; register budget ~120 <= 128 cap at (512,4) so two
// blocks (two barrier domains) co-reside per CU and overlap their stalls.
// v held as packed bf16 (16 regs). B (u frag) loaded JIT but issued FIRST so
// its waitcnt leaves the 4 W-staging loads in flight.
template<int NCHUNK>
__global__ __launch_bounds__(512, 4)
void pass1_kernel(const short* __restrict__ Wbf, const short* __restrict__ ubf,
                  const float* __restrict__ vin, float* __restrict__ part)
{
  __shared__ uint4 Wt[2][2048];     // double-buffered W tile (2 x 32KB)
  __shared__ float al[2][32][18];   // logits -> c, [parity][o][b_local]

  const int t  = threadIdx.x;
  const int l  = t & 63;
  const int w  = t >> 6;            // wave 0..7
  const int bid = blockIdx.x;
  const int bq = (bid >> 3) & 3;                    // b quadrant (16 b)
  const int cx = (bid & 7) | ((bid >> 5) << 3);     // chunk (XCD-grouped)
  const int n0 = cx * NCHUNK;

  const int bl = l & 15;
  const int b  = bq * 16 + bl;
  const int h  = l >> 4;
  const int hA = h & 1;
  const bool ld = (l < 32);

  // v as packed bf16 (n-invariant): 16 regs
  unsigned vb[16];
  #pragma unroll
  for (int q = 0; q < 8; ++q) {
    f32x4 v4 = *reinterpret_cast<const f32x4*>(vin + (size_t)b * J + (w*8+q)*16 + h*4);
    vb[2*q]   = (unsigned)f2bf(v4[0]) | ((unsigned)f2bf(v4[1]) << 16);
    vb[2*q+1] = (unsigned)f2bf(v4[2]) | ((unsigned)f2bf(v4[3]) << 16);
  }

  f32x4 acc[8];
  #pragma unroll
  for (int q = 0; q < 8; ++q) acc[q] = f32x4{0.f, 0.f, 0.f, 0.f};

  // prologue: stage tile n0 (512 threads x 4 uint4)
  {
    const uint4* src = reinterpret_cast<const uint4*>(Wbf + (size_t)n0 * (D_IN * J));
    #pragma unroll
    for (int r = 0; r < 4; ++r) Wt[0][t + r * 512] = src[t + r * 512];
  }
  __syncthreads();

  for (int nn = 0; nn < NCHUNK; ++nn) {
    const int n = n0 + nn;
    const int cur = nn & 1, nxt = cur ^ 1, par = nn & 1;
    const bool more = (nn + 1 < NCHUNK);

    // 1. B first (waitcnt for it leaves staging loads in flight), then staging
    short8 B = short8{0,0,0,0,0,0,0,0};
    if (ld) B = *reinterpret_cast<const short8*>(ubf + ((size_t)b * N_IN + n) * D_IN + hA * 8);
    uint4 s0, s1, s2, s3;
    if (more) {
      const uint4* src = reinterpret_cast<const uint4*>(Wbf + (size_t)(n + 1) * (D_IN * J));
      s0 = src[t];
      s1 = src[t + 512];
      s2 = src[t + 1024];
      s3 = src[t + 1536];
    }
    __builtin_amdgcn_sched_barrier(0);

    // 2. uhat tiles via MFMA (8 j-tiles)
    f32x4 C[8];
    const uint4* buf = Wt[cur];
    #pragma unroll
    for (int q = 0; q < 8; ++q) {
      short8 A = short8{0,0,0,0,0,0,0,0};
      if (ld) A = *reinterpret_cast<const short8*>(&buf[wp((w*8+q)*32 + 2*bl + hA)]);
      f32x4 z = f32x4{0.f, 0.f, 0.f, 0.f};
      C[q] = __builtin_amdgcn_mfma_f32_16x16x32_bf16(A, B, z, 0, 0, 0);
    }

    // 3. agreement a[b][o] = sum_k uhat*v (o = w*4+p combines q=2p,2p+1)
    {
      #pragma unroll
      for (int p = 0; p < 4; ++p) {
        float s = 0.f;
        #pragma unroll
        for (int e = 0; e < 2; ++e) {
          int q = 2 * p + e;
          float v0f = __uint_as_float(vb[2*q] << 16);
          float v1f = __uint_as_float(vb[2*q] & 0xffff0000u);
          float v2f = __uint_as_float(vb[2*q+1] << 16);
          float v3f = __uint_as_float(vb[2*q+1] & 0xffff0000u);
          s += C[q][0]*v0f + C[q][1]*v1f + C[q][2]*v2f + C[q][3]*v3f;
        }
        s += __shfl_xor(s, 16);
        s += __shfl_xor(s, 32);
        if (l < 16) al[par][w * 4 + p][l] = s;
      }
    }

    // 4. write-late staging into other buffer
    if (more) {
      Wt[nxt][t] = s0;
      Wt[nxt][t + 512] = s1;
      Wt[nxt][t + 1024] = s2;
      Wt[nxt][t + 1536] = s3;
    }

    __syncthreads();   // (B) logits staged
    {
      // softmax: 512 threads = 16 b x 32 o
      int sb = t >> 5, so = t & 31;
      float x = al[par][so][sb];
      float m = x;
      #pragma unroll
      for (int k = 1; k < 32; k <<= 1) m = fmaxf(m, __shfl_xor(m, k));
      float e = __expf(x - m);
      float sm = e;
      #pragma unroll
      for (int k = 1; k < 32; k <<= 1) sm += __shfl_xor(sm, k);
      al[par][so][sb] = e / sm;
    }
    __syncthreads();   // (C) c ready
    #pragma unroll
    for (int q = 0; q < 8; ++q) {
      float c = al[par][(w * 8 + q) >> 1][bl];
      acc[q] += C[q] * c;
    }
    // no end barrier: al parity-buffered; Wt read->overwrite separated by (B)
  }

  // epilogue: part[cx][j][b]
  #pragma unroll
  for (int q = 0; q < 8; ++q) {
    int jbase = (w * 8 + q) * 16 + h * 4;
    #pragma unroll
    for (int r = 0; r < 4; ++r)
      part[((size_t)cx * J + jbase + r) * 64 + b] = acc[q][r];
  }
}

// MODE 0: load W f32, convert, MFMA (c uniform), AND write bf16 copies (pass 0)
// MODE 2: same without writeout (fallback when ws too small)
// Round-12 proven structure, unchanged.
template<bool HAS_V, int MODE, int NCHUNK>
__global__ __launch_bounds__(1024, 1)
void pass_kernel(const float* __restrict__ uf, const float* __restrict__ Wf,
                 short* __restrict__ Wbf, short* __restrict__ ubf,
                 const float* __restrict__ vin, float* __restrict__ part)
{
  __shared__ uint4 Wt[2][2048];
  __shared__ float al[2][32][18];

  const int t  = threadIdx.x;
  const int l  = t & 63;
  const int w  = t >> 6;
  const int bid = blockIdx.x;
  const int bq = (bid >> 3) & 3;
  const int cx = (bid & 7) | ((bid >> 5) << 3);
  const int n0 = cx * NCHUNK;

  const int bl = l & 15;
  const int b  = bq * 16 + bl;
  const int h  = l >> 4;
  const int hA = h & 1;
  const bool ld = (l < 32);

  f32x4 vf[4];
  if (HAS_V) {
    #pragma unroll
    for (int q = 0; q < 4; ++q)
      vf[q] = *reinterpret_cast<const f32x4*>(vin + (size_t)b * J + (w*4+q)*16 + h*4);
  }

  int aoff[4];
  #pragma unroll
  for (int q = 0; q < 4; ++q) aoff[q] = wp(2 * ((w*4+q) * 16 + bl) + hA);

  f32x4 acc[4];
  #pragma unroll
  for (int q = 0; q < 4; ++q) acc[q] = f32x4{0.f, 0.f, 0.f, 0.f};

  const bool wq = (MODE == 0) && ((t >> 8) == bq);
  const bool uq = (MODE == 0) && (w == 0) && ld;

  short8 Bcur = short8{0,0,0,0,0,0,0,0};
  {
    float wc[16];
    const float* wsrc = Wf + (size_t)n0 * (D_IN * J) + t;
    #pragma unroll
    for (int i = 0; i < 16; ++i) wc[i] = wsrc[i * J];
    float4 a4 = {0,0,0,0}, b4 = {0,0,0,0};
    if (ld) {
      const float* up = uf + ((size_t)b * N_IN + n0) * D_IN + hA * 8;
      a4 = *reinterpret_cast<const float4*>(up);
      b4 = *reinterpret_cast<const float4*>(up + 4);
    }
    __builtin_amdgcn_sched_barrier(0);
    uint4 d0, d1;
    pack_col(wc, d0, d1);
    Wt[0][wp(2 * t)] = d0;
    Wt[0][wp(2 * t + 1)] = d1;
    if (wq) {
      uint4* gdst = reinterpret_cast<uint4*>(Wbf + (size_t)n0 * (D_IN * J));
      gdst[wp(2 * t)] = d0;
      gdst[wp(2 * t + 1)] = d1;
    }
    if (ld) {
      Bcur[0] = (short)f2bf(a4.x); Bcur[1] = (short)f2bf(a4.y);
      Bcur[2] = (short)f2bf(a4.z); Bcur[3] = (short)f2bf(a4.w);
      Bcur[4] = (short)f2bf(b4.x); Bcur[5] = (short)f2bf(b4.y);
      Bcur[6] = (short)f2bf(b4.z); Bcur[7] = (short)f2bf(b4.w);
      if (uq)
        *reinterpret_cast<short8*>(ubf + ((size_t)b * N_IN + n0) * D_IN + hA * 8) = Bcur;
    }
  }
  __syncthreads();

  for (int nn = 0; nn < NCHUNK; ++nn) {
    const int n = n0 + nn;
    const int cur = nn & 1, nxt = cur ^ 1, par = nn & 1;
    const bool more = (nn + 1 < NCHUNK);

    float wc[16];
    float4 a4 = {0,0,0,0}, b4 = {0,0,0,0};
    if (more) {
      const float* wsrc = Wf + (size_t)(n + 1) * (D_IN * J) + t;
      #pragma unroll
      for (int i = 0; i < 16; ++i) wc[i] = wsrc[i * J];
      if (ld) {
        const float* up = uf + ((size_t)b * N_IN + n + 1) * D_IN + hA * 8;
        a4 = *reinterpret_cast<const float4*>(up);
        b4 = *reinterpret_cast<const float4*>(up + 4);
      }
      __builtin_amdgcn_sched_barrier(0);
    }

    f32x4 C[4];
    const uint4* buf = Wt[cur];
    #pragma unroll
    for (int q = 0; q < 4; ++q) {
      short8 A = short8{0,0,0,0,0,0,0,0};
      if (ld) A = *reinterpret_cast<const short8*>(&buf[aoff[q]]);
      f32x4 z = f32x4{0.f, 0.f, 0.f, 0.f};
      C[q] = __builtin_amdgcn_mfma_f32_16x16x32_bf16(A, Bcur, z, 0, 0, 0);
    }

    short8 Bn = short8{0,0,0,0,0,0,0,0};
    if (more && ld) {
      Bn[0] = (short)f2bf(a4.x); Bn[1] = (short)f2bf(a4.y);
      Bn[2] = (short)f2bf(a4.z); Bn[3] = (short)f2bf(a4.w);
      Bn[4] = (short)f2bf(b4.x); Bn[5] = (short)f2bf(b4.y);
      Bn[6] = (short)f2bf(b4.z); Bn[7] = (short)f2bf(b4.w);
    }

    if (HAS_V) {
      float ap[2] = {0.f, 0.f};
      #pragma unroll
      for (int q = 0; q < 4; ++q) {
        float s = C[q][0]*vf[q][0] + C[q][1]*vf[q][1] + C[q][2]*vf[q][2] + C[q][3]*vf[q][3];
        ap[q >> 1] += s;
      }
      #pragma unroll
      for (int p = 0; p < 2; ++p) {
        float s = ap[p];
        s += __shfl_xor(s, 16);
        s += __shfl_xor(s, 32);
        if (l < 16) al[par][w * 2 + p][l] = s;
      }
      if (more) {
        uint4 d0, d1;
        pack_col(wc, d0, d1);
        Wt[nxt][wp(2 * t)] = d0;
        Wt[nxt][wp(2 * t + 1)] = d1;
        if (wq) {
          uint4* gdst = reinterpret_cast<uint4*>(Wbf + (size_t)(n + 1) * (D_IN * J));
          gdst[wp(2 * t)] = d0;
          gdst[wp(2 * t + 1)] = d1;
        }
        if (ld && uq)
          *reinterpret_cast<short8*>(ubf + ((size_t)b * N_IN + n + 1) * D_IN + hA * 8) = Bn;
      }
      __syncthreads();   // (B)
      if (t < 512) {
        int sb = t >> 5, so = t & 31;
        float x = al[par][so][sb];
        float m = x;
        #pragma unroll
        for (int k = 1; k < 32; k <<= 1) m = fmaxf(m, __shfl_xor(m, k));
        float e = __expf(x - m);
        float sm = e;
        #pragma unroll
        for (int k = 1; k < 32; k <<= 1) sm += __shfl_xor(sm, k);
        al[par][so][sb] = e / sm;
      }
      __syncthreads();   // (C)
      #pragma unroll
      for (int q = 0; q < 4; ++q) {
        float c = al[par][(w * 4 + q) >> 1][bl];
        acc[q] += C[q] * c;
      }
    } else {
      #pragma unroll
      for (int q = 0; q < 4; ++q) acc[q] += C[q];
      if (more) {
        uint4 d0, d1;
        pack_col(wc, d0, d1);
        Wt[nxt][wp(2 * t)] = d0;
        Wt[nxt][wp(2 * t + 1)] = d1;
        if (wq) {
          uint4* gdst = reinterpret_cast<uint4*>(Wbf + (size_t)(n + 1) * (D_IN * J));
          gdst[wp(2 * t)] = d0;
          gdst[wp(2 * t + 1)] = d1;
        }
        if (ld && uq)
          *reinterpret_cast<short8*>(ubf + ((size_t)b * N_IN + n + 1) * D_IN + hA * 8) = Bn;
      }
      __syncthreads();
    }
    Bcur = Bn;
  }

  // epilogue: part[cx][j][b]
  #pragma unroll
  for (int q = 0; q < 4; ++q) {
    int jbase = (w * 4 + q) * 16 + h * 4;
    #pragma unroll
    for (int r = 0; r < 4; ++r)
      part[((size_t)cx * J + jbase + r) * 64 + b] = acc[q][r];
  }
}

// Fused chunk-reduce + squash. grid = 128 (o x b-quadrant), 1024 threads.
template<int NC>
__global__ __launch_bounds__(1024)
void rsq_kernel(const float* __restrict__ part, const float* __restrict__ addv,
                float* __restrict__ out, float prescale)
{
  __shared__ float ps[2][32][17];
  __shared__ float vl[32][17];
  __shared__ float scl[16];
  const int o  = blockIdx.x >> 2;
  const int bq = blockIdx.x & 3;
  const int t  = threadIdx.x;
  {
    const int bb = t & 15;
    const int kk = (t >> 4) & 31;
    const int ch = t >> 9;         // 0/1
    const float* p = part + (size_t)(o * 32 + kk) * 64 + bq * 16 + bb;
    float s = 0.f;
    #pragma unroll 8
    for (int c = ch * (NC / 2); c < (ch + 1) * (NC / 2); ++c)
      s += p[(size_t)c * (J * 64)];
    ps[ch][kk][bb] = s;
  }
  __syncthreads();
  if (t < 512) {
    int kk = t >> 4, bb = t & 15;
    vl[kk][bb] = (ps[0][kk][bb] + ps[1][kk][bb]) * prescale;
  }
  __syncthreads();
  if (t < 16) {
    float n2 = 0.f;
    #pragma unroll
    for (int k = 0; k < 32; ++k) { float x = vl[k][t]; n2 += x * x; }
    scl[t] = sqrtf(n2) / (1.f + n2);
  }
  __syncthreads();
  if (t < 512) {
    int bb = t >> 5, kk = t & 31;
    int idx = (bq * 16 + bb) * J + o * 32 + kk;
    float val = scl[bb] * vl[kk][bb];
    if (addv) val += addv[idx];
    out[idx] = val;
  }
}

extern "C" void kernel_launch(void* const* d_in, const int* in_sizes, int n_in,
                              void* d_out, int out_size, void* d_ws, size_t ws_size,
                              hipStream_t stream)
{
  const float* u = (const float*)d_in[0];
  const float* W = (const float*)d_in[1];
  float* out = (float*)d_out;
  char* ws = (char*)d_ws;

  const size_t WBF_B = (size_t)N_IN * D_IN * J * 2;        // 64 MB
  const size_t UBF_B = (size_t)BATCH * N_IN * D_IN * 2;    // 4 MB
  const size_t SMALL = 2ull * BATCH * J * 4;               // v0+vs
  const size_t PART128 = (size_t)128 * J * 64 * 4;         // 33.5 MB
  const size_t PART64  = (size_t)64 * J * 64 * 4;          // 16.7 MB

  if (ws_size >= WBF_B + UBF_B + PART128 + SMALL) {
    short* Wbf = (short*)ws;
    short* ubf = (short*)(ws + WBF_B);
    float* part = (float*)(ws + WBF_B + UBF_B);
    float* v0 = part + (size_t)128 * J * 64;
    float* vs = v0 + BATCH * J;
    // r=0: round-12 pass0 (converts + emits Wbf/ubf)
    pass_kernel<false, 0, 32><<<256, 1024, 0, stream>>>(u, W, Wbf, ubf, nullptr, part);
    rsq_kernel<64><<<128, 1024, 0, stream>>>(part, nullptr, v0, 1.f / 32.f);
    // r=1,2: NEW 512-thread pass1, NCHUNK=16 -> grid 512 -> 2 blocks/CU
    pass1_kernel<16><<<512, 512, 0, stream>>>(Wbf, ubf, v0, part);
    rsq_kernel<128><<<128, 1024, 0, stream>>>(part, v0, vs, 1.f);
    pass1_kernel<16><<<512, 512, 0, stream>>>(Wbf, ubf, vs, part);
    rsq_kernel<128><<<128, 1024, 0, stream>>>(part, nullptr, out, 1.f);
  } else if (ws_size >= PART64 + SMALL) {
    float* part = (float*)ws;
    float* v0 = part + (size_t)64 * J * 64;
    float* vs = v0 + BATCH * J;
    pass_kernel<false, 2, 32><<<256, 1024, 0, stream>>>(u, W, nullptr, nullptr, nullptr, part);
    rsq_kernel<64><<<128, 1024, 0, stream>>>(part, nullptr, v0, 1.f / 32.f);
    pass_kernel<true, 2, 32><<<256, 1024, 0, stream>>>(u, W, nullptr, nullptr, v0, part);
    rsq_kernel<64><<<128, 1024, 0, stream>>>(part, v0, vs, 1.f);
    pass_kernel<true, 2, 32><<<256, 1024, 0, stream>>>(u, W, nullptr, nullptr, vs, part);
    rsq_kernel<64><<<128, 1024, 0, stream>>>(part, nullptr, out, 1.f);
  } else {
    float* part = (float*)ws;
    float* v0 = part + (size_t)16 * J * 64;
    float* vs = v0 + BATCH * J;
    pass_kernel<false, 2, 128><<<64, 1024, 0, stream>>>(u, W, nullptr, nullptr, nullptr, part);
    rsq_kernel<16><<<128, 1024, 0, stream>>>(part, nullptr, v0, 1.f / 32.f);
    pass_kernel<true, 2, 128><<<64, 1024, 0, stream>>>(u, W, nullptr, nullptr, v0, part);
    rsq_kernel<16><<<128, 1024, 0, stream>>>(part, v0, vs, 1.f);
    pass_kernel<true, 2, 128><<<64, 1024, 0, stream>>>(u, W, nullptr, nullptr, vs, part);
    rsq_kernel<16><<<128, 1024, 0, stream>>>(part, nullptr, out, 1.f);
  }
}

// Round 15
// 180.003 us; speedup vs baseline: 1.7815x; 1.4008x over previous
//
#include <hip/hip_runtime.h>
#include <math.h>

#define N_OUT 32
#define D_OUT 32
#define N_IN 2048
#define D_IN 16
#define BATCH 64
#define J 1024           // N_OUT*D_OUT

typedef __attribute__((ext_vector_type(8))) short short8;   // 8 bf16 (4 VGPR)
typedef __attribute__((ext_vector_type(4))) float f32x4;    // MFMA C/D

// f32 -> bf16 RNE
__device__ __forceinline__ unsigned short f2bf(float f) {
  unsigned int x = __float_as_uint(f);
  return (unsigned short)((x + 0x7FFFu + ((x >> 16) & 1u)) >> 16);
}

// 16B-unit swizzle inside one n-tile (2048 units): XOR bit0 with bit3
__device__ __forceinline__ int wp(int u) { return u ^ ((u >> 3) & 1); }

__device__ __forceinline__ void pack_col(const float* wc, uint4& d0, uint4& d1) {
  d0.x = (unsigned)f2bf(wc[0])  | ((unsigned)f2bf(wc[1])  << 16);
  d0.y = (unsigned)f2bf(wc[2])  | ((unsigned)f2bf(wc[3])  << 16);
  d0.z = (unsigned)f2bf(wc[4])  | ((unsigned)f2bf(wc[5])  << 16);
  d0.w = (unsigned)f2bf(wc[6])  | ((unsigned)f2bf(wc[7])  << 16);
  d1.x = (unsigned)f2bf(wc[8])  | ((unsigned)f2bf(wc[9])  << 16);
  d1.y = (unsigned)f2bf(wc[10]) | ((unsigned)f2bf(wc[11]) << 16);
  d1.z = (unsigned)f2bf(wc[12]) | ((unsigned)f2bf(wc[13]) << 16);
  d1.w = (unsigned)f2bf(wc[14]) | ((unsigned)f2bf(wc[15]) << 16);
}

__device__ __forceinline__ short8 pack_u(const float4& a4, const float4& b4) {
  short8 B;
  B[0] = (short)f2bf(a4.x); B[1] = (short)f2bf(a4.y);
  B[2] = (short)f2bf(a4.z); B[3] = (short)f2bf(a4.w);
  B[4] = (short)f2bf(b4.x); B[5] = (short)f2bf(b4.y);
  B[6] = (short)f2bf(b4.z); B[7] = (short)f2bf(b4.w);
  return B;
}

// ============ pass0p: pass 0 with 2 n per barrier (quad-buffered) ============
// r12's paired-n trick applied to the convert pass: 1 barrier / 2 n, 32-load
// batches for MLP depth, in-place MFMA accumulation (acc[4] only; no C regs).
// Live state ~100 regs <= 128 cap. MODE 0 emits Wbf/ubf; MODE 2 does not.
template<int MODE>
__global__ __launch_bounds__(1024, 1)
void pass0p_kernel(const float* __restrict__ uf, const float* __restrict__ Wf,
                   short* __restrict__ Wbf, short* __restrict__ ubf,
                   float* __restrict__ part)
{
  __shared__ uint4 Wt[4][2048];     // quad-buffered W tiles (4 x 32KB = 128KB)

  const int t  = threadIdx.x;
  const int l  = t & 63;
  const int w  = t >> 6;            // wave 0..15
  const int bid = blockIdx.x;
  const int bq = (bid >> 3) & 3;                    // b quadrant (16 b)
  const int cx = (bid & 7) | ((bid >> 5) << 3);     // chunk (XCD-grouped)
  const int n0 = cx * 32;

  const int bl = l & 15;
  const int b  = bq * 16 + bl;
  const int h  = l >> 4;
  const int hA = h & 1;
  const bool ld = (l < 32);
  const bool wq = (MODE == 0) && ((t >> 8) == bq);   // this block's Wbf quarter
  const bool uq = (MODE == 0) && (w == 0) && ld;     // wave 0 writes ubf

  int aoff[4];
  #pragma unroll
  for (int q = 0; q < 4; ++q) aoff[q] = wp(2 * ((w*4+q) * 16 + bl) + hA);

  f32x4 acc[4];
  #pragma unroll
  for (int q = 0; q < 4; ++q) acc[q] = f32x4{0.f, 0.f, 0.f, 0.f};

  short8 Ba = short8{0,0,0,0,0,0,0,0}, Bb = short8{0,0,0,0,0,0,0,0};

  // prologue: pair (n0, n0+1) -> Wt[0], Wt[1]
  {
    float wa[16], wb[16];
    const float* sa = Wf + (size_t)n0 * (D_IN * J) + t;
    const float* sb = Wf + (size_t)(n0 + 1) * (D_IN * J) + t;
    #pragma unroll
    for (int i = 0; i < 16; ++i) wa[i] = sa[i * J];
    #pragma unroll
    for (int i = 0; i < 16; ++i) wb[i] = sb[i * J];
    float4 ua0 = {0,0,0,0}, ua1 = {0,0,0,0}, ub0 = {0,0,0,0}, ub1 = {0,0,0,0};
    if (ld) {
      const float* upa = uf + ((size_t)b * N_IN + n0) * D_IN + hA * 8;
      ua0 = *reinterpret_cast<const float4*>(upa);
      ua1 = *reinterpret_cast<const float4*>(upa + 4);
      const float* upb = uf + ((size_t)b * N_IN + n0 + 1) * D_IN + hA * 8;
      ub0 = *reinterpret_cast<const float4*>(upb);
      ub1 = *reinterpret_cast<const float4*>(upb + 4);
    }
    __builtin_amdgcn_sched_barrier(0);   // all loads issued before packing
    uint4 d0, d1;
    pack_col(wa, d0, d1);
    Wt[0][wp(2 * t)] = d0;
    Wt[0][wp(2 * t + 1)] = d1;
    if (wq) {
      uint4* g = reinterpret_cast<uint4*>(Wbf + (size_t)n0 * (D_IN * J));
      g[wp(2 * t)] = d0;
      g[wp(2 * t + 1)] = d1;
    }
    pack_col(wb, d0, d1);
    Wt[1][wp(2 * t)] = d0;
    Wt[1][wp(2 * t + 1)] = d1;
    if (wq) {
      uint4* g = reinterpret_cast<uint4*>(Wbf + (size_t)(n0 + 1) * (D_IN * J));
      g[wp(2 * t)] = d0;
      g[wp(2 * t + 1)] = d1;
    }
    if (ld) {
      Ba = pack_u(ua0, ua1);
      Bb = pack_u(ub0, ub1);
      if (uq) {
        *reinterpret_cast<short8*>(ubf + ((size_t)b * N_IN + n0) * D_IN + hA * 8) = Ba;
        *reinterpret_cast<short8*>(ubf + ((size_t)b * N_IN + n0 + 1) * D_IN + hA * 8) = Bb;
      }
    }
  }
  __syncthreads();

  for (int ss = 0; ss < 16; ++ss) {
    const int na = n0 + 2 * ss;
    const int p = ss & 1;             // read pair base 2p, write pair 2(1-p)
    const bool more = (ss + 1 < 16);

    // 1. issue next-pair loads (32 W f32 + 4 u float4), then fence
    float wa[16], wb[16];
    float4 ua0 = {0,0,0,0}, ua1 = {0,0,0,0}, ub0 = {0,0,0,0}, ub1 = {0,0,0,0};
    if (more) {
      const float* sa = Wf + (size_t)(na + 2) * (D_IN * J) + t;
      const float* sb = Wf + (size_t)(na + 3) * (D_IN * J) + t;
      #pragma unroll
      for (int i = 0; i < 16; ++i) wa[i] = sa[i * J];
      #pragma unroll
      for (int i = 0; i < 16; ++i) wb[i] = sb[i * J];
      if (ld) {
        const float* upa = uf + ((size_t)b * N_IN + na + 2) * D_IN + hA * 8;
        ua0 = *reinterpret_cast<const float4*>(upa);
        ua1 = *reinterpret_cast<const float4*>(upa + 4);
        const float* upb = uf + ((size_t)b * N_IN + na + 3) * D_IN + hA * 8;
        ub0 = *reinterpret_cast<const float4*>(upb);
        ub1 = *reinterpret_cast<const float4*>(upb + 4);
      }
      __builtin_amdgcn_sched_barrier(0);
    }

    // 2. MFMA both n's, accumulating in place (no separate C regs)
    {
      const uint4* bufA = Wt[2 * p];
      const uint4* bufB = Wt[2 * p + 1];
      #pragma unroll
      for (int q = 0; q < 4; ++q) {
        short8 A = short8{0,0,0,0,0,0,0,0};
        if (ld) A = *reinterpret_cast<const short8*>(&bufA[aoff[q]]);
        acc[q] = __builtin_amdgcn_mfma_f32_16x16x32_bf16(A, Ba, acc[q], 0, 0, 0);
      }
      #pragma unroll
      for (int q = 0; q < 4; ++q) {
        short8 A = short8{0,0,0,0,0,0,0,0};
        if (ld) A = *reinterpret_cast<const short8*>(&bufB[aoff[q]]);
        acc[q] = __builtin_amdgcn_mfma_f32_16x16x32_bf16(A, Bb, acc[q], 0, 0, 0);
      }
    }

    // 3. write-late next pair into the other quad pair (+ global emission)
    short8 Bna = short8{0,0,0,0,0,0,0,0}, Bnb = short8{0,0,0,0,0,0,0,0};
    if (more) {
      uint4 d0, d1;
      pack_col(wa, d0, d1);
      Wt[2 * (1 - p)][wp(2 * t)] = d0;
      Wt[2 * (1 - p)][wp(2 * t + 1)] = d1;
      if (wq) {
        uint4* g = reinterpret_cast<uint4*>(Wbf + (size_t)(na + 2) * (D_IN * J));
        g[wp(2 * t)] = d0;
        g[wp(2 * t + 1)] = d1;
      }
      pack_col(wb, d0, d1);
      Wt[2 * (1 - p) + 1][wp(2 * t)] = d0;
      Wt[2 * (1 - p) + 1][wp(2 * t + 1)] = d1;
      if (wq) {
        uint4* g = reinterpret_cast<uint4*>(Wbf + (size_t)(na + 3) * (D_IN * J));
        g[wp(2 * t)] = d0;
        g[wp(2 * t + 1)] = d1;
      }
      if (ld) {
        Bna = pack_u(ua0, ua1);
        Bnb = pack_u(ub0, ub1);
        if (uq) {
          *reinterpret_cast<short8*>(ubf + ((size_t)b * N_IN + na + 2) * D_IN + hA * 8) = Bna;
          *reinterpret_cast<short8*>(ubf + ((size_t)b * N_IN + na + 3) * D_IN + hA * 8) = Bnb;
        }
      }
    }

    __syncthreads();   // separates this iter's reads/writes from next iter's
    Ba = Bna;
    Bb = Bnb;
  }

  // epilogue: part[cx][j][b]
  #pragma unroll
  for (int q = 0; q < 4; ++q) {
    int jbase = (w * 4 + q) * 16 + h * 4;
    #pragma unroll
    for (int r = 0; r < 4; ++r)
      part[((size_t)cx * J + jbase + r) * 64 + b] = acc[q][r];
  }
}

// MODE 0: load W f32, convert in-kernel, AND write bf16 copies out
// MODE 1: reg-staged pre-converted Wbf/ubf, 2 n per barrier pair (passes 1,2)
// MODE 2: like MODE 0 without writeout (fallback when ws too small)
// Round-12 proven structure, unchanged.
template<bool HAS_V, int MODE, int NCHUNK>
__global__ __launch_bounds__(1024, 1)
void pass_kernel(const float* __restrict__ uf, const float* __restrict__ Wf,
                 short* __restrict__ Wbf, short* __restrict__ ubf,
                 const float* __restrict__ vin, float* __restrict__ part)
{
  constexpr int NBUF = (MODE == 1) ? 4 : 2;
  __shared__ uint4 Wt[NBUF][2048];        // W tiles (32KB each)
  __shared__ float al[2][2][32][18];      // logits -> c, [parity][npair][o][b]

  const int t  = threadIdx.x;
  const int l  = t & 63;
  const int w  = t >> 6;            // wave 0..15
  const int bid = blockIdx.x;
  const int bq = (bid >> 3) & 3;                    // b quadrant (16 b)
  const int cx = (bid & 7) | ((bid >> 5) << 3);     // chunk (XCD-grouped)
  const int n0 = cx * NCHUNK;

  const int bl = l & 15;            // D col = b_local
  const int b  = bq * 16 + bl;      // global b
  const int h  = l >> 4;            // 0..3: D rows 4h..4h+3
  const int hA = h & 1;             // k-half (i 0-7 / 8-15) for lanes < 32
  const bool ld = (l < 32);

  f32x4 vf[4];
  if (HAS_V) {
    #pragma unroll
    for (int q = 0; q < 4; ++q)
      vf[q] = *reinterpret_cast<const f32x4*>(vin + (size_t)b * J + (w*4+q)*16 + h*4);
  }

  int aoff[4];
  #pragma unroll
  for (int q = 0; q < 4; ++q) aoff[q] = wp(2 * ((w*4+q) * 16 + bl) + hA);

  f32x4 acc[4];
  #pragma unroll
  for (int q = 0; q < 4; ++q) acc[q] = f32x4{0.f, 0.f, 0.f, 0.f};

  if constexpr (MODE == 1) {
    // ============ MODE 1: paired-n, quad-buffered ============
    constexpr int NS = NCHUNK / 2;
    short8 Ba = short8{0,0,0,0,0,0,0,0}, Bb = short8{0,0,0,0,0,0,0,0};
    {
      const uint4* srcA = reinterpret_cast<const uint4*>(Wbf + (size_t)n0 * (D_IN * J));
      Wt[0][t] = srcA[t];
      Wt[0][t + 1024] = srcA[t + 1024];
      const uint4* srcB = reinterpret_cast<const uint4*>(Wbf + (size_t)(n0 + 1) * (D_IN * J));
      Wt[1][t] = srcB[t];
      Wt[1][t + 1024] = srcB[t + 1024];
      if (ld) {
        Ba = *reinterpret_cast<const short8*>(ubf + ((size_t)b * N_IN + n0) * D_IN + hA * 8);
        Bb = *reinterpret_cast<const short8*>(ubf + ((size_t)b * N_IN + n0 + 1) * D_IN + hA * 8);
      }
    }
    __syncthreads();

    for (int ss = 0; ss < NS; ++ss) {
      const int na = n0 + 2 * ss;
      const int p = ss & 1;
      const int par = ss & 1;
      const bool more = (ss + 1 < NS);

      uint4 sa0, sa1, sb0, sb1;
      short8 Bna = short8{0,0,0,0,0,0,0,0}, Bnb = short8{0,0,0,0,0,0,0,0};
      if (more) {
        const uint4* srcA = reinterpret_cast<const uint4*>(Wbf + (size_t)(na + 2) * (D_IN * J));
        sa0 = srcA[t];
        sa1 = srcA[t + 1024];
        const uint4* srcB = reinterpret_cast<const uint4*>(Wbf + (size_t)(na + 3) * (D_IN * J));
        sb0 = srcB[t];
        sb1 = srcB[t + 1024];
        if (ld) {
          Bna = *reinterpret_cast<const short8*>(ubf + ((size_t)b * N_IN + na + 2) * D_IN + hA * 8);
          Bnb = *reinterpret_cast<const short8*>(ubf + ((size_t)b * N_IN + na + 3) * D_IN + hA * 8);
        }
        __builtin_amdgcn_sched_barrier(0);
      }

      f32x4 Ca[4], Cb[4];
      {
        const uint4* bufA = Wt[2 * p];
        const uint4* bufB = Wt[2 * p + 1];
        #pragma unroll
        for (int q = 0; q < 4; ++q) {
          short8 A = short8{0,0,0,0,0,0,0,0};
          if (ld) A = *reinterpret_cast<const short8*>(&bufA[aoff[q]]);
          f32x4 z = f32x4{0.f, 0.f, 0.f, 0.f};
          Ca[q] = __builtin_amdgcn_mfma_f32_16x16x32_bf16(A, Ba, z, 0, 0, 0);
        }
        #pragma unroll
        for (int q = 0; q < 4; ++q) {
          short8 A = short8{0,0,0,0,0,0,0,0};
          if (ld) A = *reinterpret_cast<const short8*>(&bufB[aoff[q]]);
          f32x4 z = f32x4{0.f, 0.f, 0.f, 0.f};
          Cb[q] = __builtin_amdgcn_mfma_f32_16x16x32_bf16(A, Bb, z, 0, 0, 0);
        }
      }

      {
        float apa[2] = {0.f, 0.f}, apb[2] = {0.f, 0.f};
        #pragma unroll
        for (int q = 0; q < 4; ++q) {
          apa[q >> 1] += Ca[q][0]*vf[q][0] + Ca[q][1]*vf[q][1] + Ca[q][2]*vf[q][2] + Ca[q][3]*vf[q][3];
          apb[q >> 1] += Cb[q][0]*vf[q][0] + Cb[q][1]*vf[q][1] + Cb[q][2]*vf[q][2] + Cb[q][3]*vf[q][3];
        }
        #pragma unroll
        for (int p2 = 0; p2 < 2; ++p2) {
          float sa = apa[p2], sb = apb[p2];
          sa += __shfl_xor(sa, 16);
          sa += __shfl_xor(sa, 32);
          sb += __shfl_xor(sb, 16);
          sb += __shfl_xor(sb, 32);
          if (l < 16) {
            al[par][0][w * 2 + p2][l] = sa;
            al[par][1][w * 2 + p2][l] = sb;
          }
        }
      }

      if (more) {
        Wt[2 * (1 - p)][t] = sa0;
        Wt[2 * (1 - p)][t + 1024] = sa1;
        Wt[2 * (1 - p) + 1][t] = sb0;
        Wt[2 * (1 - p) + 1][t + 1024] = sb1;
      }

      __syncthreads();   // (B) logits staged
      {
        int npair = t >> 9, sb2 = (t >> 5) & 15, so = t & 31;
        float x = al[par][npair][so][sb2];
        float m = x;
        #pragma unroll
        for (int k = 1; k < 32; k <<= 1) m = fmaxf(m, __shfl_xor(m, k));
        float e = __expf(x - m);
        float sm = e;
        #pragma unroll
        for (int k = 1; k < 32; k <<= 1) sm += __shfl_xor(sm, k);
        al[par][npair][so][sb2] = e / sm;
      }
      __syncthreads();   // (C) c ready
      #pragma unroll
      for (int q = 0; q < 4; ++q) {
        float ca = al[par][0][(w * 4 + q) >> 1][bl];
        float cb = al[par][1][(w * 4 + q) >> 1][bl];
        acc[q] += Ca[q] * ca + Cb[q] * cb;
      }
      Ba = Bna;
      Bb = Bnb;
    }
  } else {
    // ============ MODE 0/2: f32 load + convert, MLP-forced ============
    const bool wq = (MODE == 0) && ((t >> 8) == bq);
    const bool uq = (MODE == 0) && (w == 0) && ld;

    short8 Bcur = short8{0,0,0,0,0,0,0,0};
    {
      float wc[16];
      const float* wsrc = Wf + (size_t)n0 * (D_IN * J) + t;
      #pragma unroll
      for (int i = 0; i < 16; ++i) wc[i] = wsrc[i * J];
      float4 a4 = {0,0,0,0}, b4 = {0,0,0,0};
      if (ld) {
        const float* up = uf + ((size_t)b * N_IN + n0) * D_IN + hA * 8;
        a4 = *reinterpret_cast<const float4*>(up);
        b4 = *reinterpret_cast<const float4*>(up + 4);
      }
      __builtin_amdgcn_sched_barrier(0);
      uint4 d0, d1;
      pack_col(wc, d0, d1);
      Wt[0][wp(2 * t)] = d0;
      Wt[0][wp(2 * t + 1)] = d1;
      if (wq) {
        uint4* gdst = reinterpret_cast<uint4*>(Wbf + (size_t)n0 * (D_IN * J));
        gdst[wp(2 * t)] = d0;
        gdst[wp(2 * t + 1)] = d1;
      }
      if (ld) {
        Bcur = pack_u(a4, b4);
        if (uq)
          *reinterpret_cast<short8*>(ubf + ((size_t)b * N_IN + n0) * D_IN + hA * 8) = Bcur;
      }
    }
    __syncthreads();

    for (int nn = 0; nn < NCHUNK; ++nn) {
      const int n = n0 + nn;
      const int cur = nn & 1, nxt = cur ^ 1, par = nn & 1;
      const bool more = (nn + 1 < NCHUNK);

      float wc[16];
      float4 a4 = {0,0,0,0}, b4 = {0,0,0,0};
      if (more) {
        const float* wsrc = Wf + (size_t)(n + 1) * (D_IN * J) + t;
        #pragma unroll
        for (int i = 0; i < 16; ++i) wc[i] = wsrc[i * J];
        if (ld) {
          const float* up = uf + ((size_t)b * N_IN + n + 1) * D_IN + hA * 8;
          a4 = *reinterpret_cast<const float4*>(up);
          b4 = *reinterpret_cast<const float4*>(up + 4);
        }
        __builtin_amdgcn_sched_barrier(0);
      }

      f32x4 C[4];
      const uint4* buf = Wt[cur];
      #pragma unroll
      for (int q = 0; q < 4; ++q) {
        short8 A = short8{0,0,0,0,0,0,0,0};
        if (ld) A = *reinterpret_cast<const short8*>(&buf[aoff[q]]);
        f32x4 z = f32x4{0.f, 0.f, 0.f, 0.f};
        C[q] = __builtin_amdgcn_mfma_f32_16x16x32_bf16(A, Bcur, z, 0, 0, 0);
      }

      short8 Bn = short8{0,0,0,0,0,0,0,0};
      if (more && ld) Bn = pack_u(a4, b4);

      if (HAS_V) {
        float ap[2] = {0.f, 0.f};
        #pragma unroll
        for (int q = 0; q < 4; ++q) {
          float s = C[q][0]*vf[q][0] + C[q][1]*vf[q][1] + C[q][2]*vf[q][2] + C[q][3]*vf[q][3];
          ap[q >> 1] += s;
        }
        #pragma unroll
        for (int p = 0; p < 2; ++p) {
          float s = ap[p];
          s += __shfl_xor(s, 16);
          s += __shfl_xor(s, 32);
          if (l < 16) al[par][0][w * 2 + p][l] = s;
        }
        if (more) {
          uint4 d0, d1;
          pack_col(wc, d0, d1);
          Wt[nxt][wp(2 * t)] = d0;
          Wt[nxt][wp(2 * t + 1)] = d1;
          if (wq) {
            uint4* gdst = reinterpret_cast<uint4*>(Wbf + (size_t)(n + 1) * (D_IN * J));
            gdst[wp(2 * t)] = d0;
            gdst[wp(2 * t + 1)] = d1;
          }
          if (ld && uq)
            *reinterpret_cast<short8*>(ubf + ((size_t)b * N_IN + n + 1) * D_IN + hA * 8) = Bn;
        }
        __syncthreads();   // (B)
        if (t < 512) {
          int sb = t >> 5, so = t & 31;
          float x = al[par][0][so][sb];
          float m = x;
          #pragma unroll
          for (int k = 1; k < 32; k <<= 1) m = fmaxf(m, __shfl_xor(m, k));
          float e = __expf(x - m);
          float sm = e;
          #pragma unroll
          for (int k = 1; k < 32; k <<= 1) sm += __shfl_xor(sm, k);
          al[par][0][so][sb] = e / sm;
        }
        __syncthreads();   // (C)
        #pragma unroll
        for (int q = 0; q < 4; ++q) {
          float c = al[par][0][(w * 4 + q) >> 1][bl];
          acc[q] += C[q] * c;
        }
      } else {
        #pragma unroll
        for (int q = 0; q < 4; ++q) acc[q] += C[q];
        if (more) {
          uint4 d0, d1;
          pack_col(wc, d0, d1);
          Wt[nxt][wp(2 * t)] = d0;
          Wt[nxt][wp(2 * t + 1)] = d1;
          if (wq) {
            uint4* gdst = reinterpret_cast<uint4*>(Wbf + (size_t)(n + 1) * (D_IN * J));
            gdst[wp(2 * t)] = d0;
            gdst[wp(2 * t + 1)] = d1;
          }
          if (ld && uq)
            *reinterpret_cast<short8*>(ubf + ((size_t)b * N_IN + n + 1) * D_IN + hA * 8) = Bn;
        }
        __syncthreads();
      }
      Bcur = Bn;
    }
  }

  // epilogue: part[cx][j][b]
  #pragma unroll
  for (int q = 0; q < 4; ++q) {
    int jbase = (w * 4 + q) * 16 + h * 4;
    #pragma unroll
    for (int r = 0; r < 4; ++r)
      part[((size_t)cx * J + jbase + r) * 64 + b] = acc[q][r];
  }
}

// Fused chunk-reduce + squash. grid = 128 (o x b-quadrant), 1024 threads.
template<int NC>
__global__ __launch_bounds__(1024)
void rsq_kernel(const float* __restrict__ part, const float* __restrict__ addv,
                float* __restrict__ out, float prescale)
{
  __shared__ float ps[2][32][17];
  __shared__ float vl[32][17];
  __shared__ float scl[16];
  const int o  = blockIdx.x >> 2;
  const int bq = blockIdx.x & 3;
  const int t  = threadIdx.x;
  {
    const int bb = t & 15;
    const int kk = (t >> 4) & 31;
    const int ch = t >> 9;         // 0/1
    const float* p = part + (size_t)(o * 32 + kk) * 64 + bq * 16 + bb;
    float s = 0.f;
    #pragma unroll 8
    for (int c = ch * (NC / 2); c < (ch + 1) * (NC / 2); ++c)
      s += p[(size_t)c * (J * 64)];
    ps[ch][kk][bb] = s;
  }
  __syncthreads();
  if (t < 512) {
    int kk = t >> 4, bb = t & 15;
    vl[kk][bb] = (ps[0][kk][bb] + ps[1][kk][bb]) * prescale;
  }
  __syncthreads();
  if (t < 16) {
    float n2 = 0.f;
    #pragma unroll
    for (int k = 0; k < 32; ++k) { float x = vl[k][t]; n2 += x * x; }
    scl[t] = sqrtf(n2) / (1.f + n2);
  }
  __syncthreads();
  if (t < 512) {
    int bb = t >> 5, kk = t & 31;
    int idx = (bq * 16 + bb) * J + o * 32 + kk;
    float val = scl[bb] * vl[kk][bb];
    if (addv) val += addv[idx];
    out[idx] = val;
  }
}

extern "C" void kernel_launch(void* const* d_in, const int* in_sizes, int n_in,
                              void* d_out, int out_size, void* d_ws, size_t ws_size,
                              hipStream_t stream)
{
  const float* u = (const float*)d_in[0];
  const float* W = (const float*)d_in[1];
  float* out = (float*)d_out;
  char* ws = (char*)d_ws;

  const size_t WBF_B = (size_t)N_IN * D_IN * J * 2;        // 64 MB
  const size_t UBF_B = (size_t)BATCH * N_IN * D_IN * 2;    // 4 MB
  const size_t SMALL = 2ull * BATCH * J * 4;               // v0+vs
  const size_t PART64 = (size_t)64 * J * 64 * 4;           // 16.7 MB (NC=64)

  if (ws_size >= WBF_B + UBF_B + PART64 + SMALL) {
    short* Wbf = (short*)ws;
    short* ubf = (short*)(ws + WBF_B);
    float* part = (float*)(ws + WBF_B + UBF_B);
    float* v0 = part + (size_t)64 * J * 64;
    float* vs = v0 + BATCH * J;
    // r=0: NEW paired-n pass0 (converts + emits Wbf/ubf, 1 barrier per 2 n)
    pass0p_kernel<0><<<256, 1024, 0, stream>>>(u, W, Wbf, ubf, part);
    rsq_kernel<64><<<128, 1024, 0, stream>>>(part, nullptr, v0, 1.f / 32.f);
    // r=1,2: round-12 paired-n MODE1
    pass_kernel<true, 1, 32><<<256, 1024, 0, stream>>>(u, W, Wbf, ubf, v0, part);
    rsq_kernel<64><<<128, 1024, 0, stream>>>(part, v0, vs, 1.f);
    pass_kernel<true, 1, 32><<<256, 1024, 0, stream>>>(u, W, Wbf, ubf, vs, part);
    rsq_kernel<64><<<128, 1024, 0, stream>>>(part, nullptr, out, 1.f);
  } else if (ws_size >= PART64 + SMALL) {
    float* part = (float*)ws;
    float* v0 = part + (size_t)64 * J * 64;
    float* vs = v0 + BATCH * J;
    pass_kernel<false, 2, 32><<<256, 1024, 0, stream>>>(u, W, nullptr, nullptr, nullptr, part);
    rsq_kernel<64><<<128, 1024, 0, stream>>>(part, nullptr, v0, 1.f / 32.f);
    pass_kernel<true, 2, 32><<<256, 1024, 0, stream>>>(u, W, nullptr, nullptr, v0, part);
    rsq_kernel<64><<<128, 1024, 0, stream>>>(part, v0, vs, 1.f);
    pass_kernel<true, 2, 32><<<256, 1024, 0, stream>>>(u, W, nullptr, nullptr, vs, part);
    rsq_kernel<64><<<128, 1024, 0, stream>>>(part, nullptr, out, 1.f);
  } else {
    float* part = (float*)ws;
    float* v0 = part + (size_t)16 * J * 64;
    float* vs = v0 + BATCH * J;
    pass_kernel<false, 2, 128><<<64, 1024, 0, stream>>>(u, W, nullptr, nullptr, nullptr, part);
    rsq_kernel<16><<<128, 1024, 0, stream>>>(part, nullptr, v0, 1.f / 32.f);
    pass_kernel<true, 2, 128><<<64, 1024, 0, stream>>>(u, W, nullptr, nullptr, v0, part);
    rsq_kernel<16><<<128, 1024, 0, stream>>>(part, v0, vs, 1.f);
    pass_kernel<true, 2, 128><<<64, 1024, 0, stream>>>(u, W, nullptr, nullptr, vs, part);
    rsq_kernel<16><<<128, 1024, 0, stream>>>(part, nullptr, out, 1.f);
  }
}

// Round 16
// 158.506 us; speedup vs baseline: 2.0231x; 1.1356x over previous
//
#include <hip/hip_runtime.h>
#include <math.h>

#define N_OUT 32
#define D_OUT 32
#define N_IN 2048
#define D_IN 16
#define BATCH 64
#define J 1024           // N_OUT*D_OUT

typedef __attribute__((ext_vector_type(8))) short short8;    // 8 bf16 (4 VGPR)
typedef __attribute__((ext_vector_type(4))) float f32x4;     // 16x16 C/D
typedef __attribute__((ext_vector_type(16))) float f32x16;   // 32x32 C/D

// f32 -> bf16 RNE
__device__ __forceinline__ unsigned short f2bf(float f) {
  unsigned int x = __float_as_uint(f);
  return (unsigned short)((x + 0x7FFFu + ((x >> 16) & 1u)) >> 16);
}

// 16B-unit swizzle inside one n-tile (2048 units): XOR bit0 with bit3
__device__ __forceinline__ int wp(int u) { return u ^ ((u >> 3) & 1); }

__device__ __forceinline__ void pack_col(const float* wc, uint4& d0, uint4& d1) {
  d0.x = (unsigned)f2bf(wc[0])  | ((unsigned)f2bf(wc[1])  << 16);
  d0.y = (unsigned)f2bf(wc[2])  | ((unsigned)f2bf(wc[3])  << 16);
  d0.z = (unsigned)f2bf(wc[4])  | ((unsigned)f2bf(wc[5])  << 16);
  d0.w = (unsigned)f2bf(wc[6])  | ((unsigned)f2bf(wc[7])  << 16);
  d1.x = (unsigned)f2bf(wc[8])  | ((unsigned)f2bf(wc[9])  << 16);
  d1.y = (unsigned)f2bf(wc[10]) | ((unsigned)f2bf(wc[11]) << 16);
  d1.z = (unsigned)f2bf(wc[12]) | ((unsigned)f2bf(wc[13]) << 16);
  d1.w = (unsigned)f2bf(wc[14]) | ((unsigned)f2bf(wc[15]) << 16);
}

__device__ __forceinline__ short8 pack_u(const float4& a4, const float4& b4) {
  short8 B;
  B[0] = (short)f2bf(a4.x); B[1] = (short)f2bf(a4.y);
  B[2] = (short)f2bf(a4.z); B[3] = (short)f2bf(a4.w);
  B[4] = (short)f2bf(b4.x); B[5] = (short)f2bf(b4.y);
  B[6] = (short)f2bf(b4.z); B[7] = (short)f2bf(b4.w);
  return B;
}

__device__ __forceinline__ f32x16 zero16() {
  f32x16 z;
  #pragma unroll
  for (int i = 0; i < 16; ++i) z[i] = 0.f;
  return z;
}

// ================== 32x32x16 decomposition ==================
// Block: 1024 threads = 32 b (one half) x 1024 j x 16 n. grid 256 = 2 bh x 128 cx.
// Wave w owns j in [w*64, w*64+64): two 32x32 tiles (q=0,1) -> o = w*2+q.
// MFMA 32x32x16: K=16 == D_IN exactly (no zero-padding, all 64 lanes active).
// A-frag: row j_loc = l&31, k = (l>>5)*8+e  (analogous to verified 16x16x32 map)
// B-frag: col b_loc = l&31, k = (l>>5)*8+e
// C/D:    col = l&31, row = (r&3)+8*(r>>2)+4*(l>>5)   [guide m74/m101]

// pass0w: c-uniform pass + bf16 emission. Paired-n (1 barrier / 2 n), in-place acc.
template<int MODE>   // 0: emit Wbf/ubf
__global__ __launch_bounds__(1024, 1)
void pass0w_kernel(const float* __restrict__ uf, const float* __restrict__ Wf,
                   short* __restrict__ Wbf, short* __restrict__ ubf,
                   float* __restrict__ part)
{
  __shared__ uint4 Wt[4][2048];     // quad-buffered (4 x 32KB)

  const int t  = threadIdx.x;
  const int l  = t & 63;
  const int w  = t >> 6;
  const int bid = blockIdx.x;
  const int bh = (bid >> 3) & 1;                    // b half (32 b)
  const int cx = (bid & 7) | ((bid >> 4) << 3);     // chunk 0..127 (XCD-paired)
  const int n0 = cx * 16;

  const int bl = l & 31;
  const int b  = bh * 32 + bl;
  const int kh = l >> 5;            // k-half: i = kh*8 .. kh*8+7
  const bool wq = (MODE == 0) && ((t >> 9) == bh);  // Wbf writer half (by t)
  const bool uq = (MODE == 0) && (w == 0);          // ubf writer (wave 0 covers 32b x 2kh)

  int aoff[2];
  #pragma unroll
  for (int q = 0; q < 2; ++q) aoff[q] = wp(2 * (w * 64 + q * 32 + bl) + kh);

  f32x16 acc[2];
  acc[0] = zero16();
  acc[1] = zero16();

  short8 Ba, Bb;

  // prologue: pair (n0, n0+1) -> Wt[0], Wt[1]
  {
    float wa[16], wb[16];
    const float* sa = Wf + (size_t)n0 * (D_IN * J) + t;
    const float* sb = Wf + (size_t)(n0 + 1) * (D_IN * J) + t;
    #pragma unroll
    for (int i = 0; i < 16; ++i) wa[i] = sa[i * J];
    #pragma unroll
    for (int i = 0; i < 16; ++i) wb[i] = sb[i * J];
    const float* upa = uf + ((size_t)b * N_IN + n0) * D_IN + kh * 8;
    float4 ua0 = *reinterpret_cast<const float4*>(upa);
    float4 ua1 = *reinterpret_cast<const float4*>(upa + 4);
    const float* upb = uf + ((size_t)b * N_IN + n0 + 1) * D_IN + kh * 8;
    float4 ub0 = *reinterpret_cast<const float4*>(upb);
    float4 ub1 = *reinterpret_cast<const float4*>(upb + 4);
    __builtin_amdgcn_sched_barrier(0);
    uint4 d0, d1;
    pack_col(wa, d0, d1);
    Wt[0][wp(2 * t)] = d0;
    Wt[0][wp(2 * t + 1)] = d1;
    if (wq) {
      uint4* g = reinterpret_cast<uint4*>(Wbf + (size_t)n0 * (D_IN * J));
      g[wp(2 * t)] = d0;
      g[wp(2 * t + 1)] = d1;
    }
    pack_col(wb, d0, d1);
    Wt[1][wp(2 * t)] = d0;
    Wt[1][wp(2 * t + 1)] = d1;
    if (wq) {
      uint4* g = reinterpret_cast<uint4*>(Wbf + (size_t)(n0 + 1) * (D_IN * J));
      g[wp(2 * t)] = d0;
      g[wp(2 * t + 1)] = d1;
    }
    Ba = pack_u(ua0, ua1);
    Bb = pack_u(ub0, ub1);
    if (uq) {
      *reinterpret_cast<short8*>(ubf + ((size_t)b * N_IN + n0) * D_IN + kh * 8) = Ba;
      *reinterpret_cast<short8*>(ubf + ((size_t)b * N_IN + n0 + 1) * D_IN + kh * 8) = Bb;
    }
  }
  __syncthreads();

  for (int ss = 0; ss < 8; ++ss) {
    const int na = n0 + 2 * ss;
    const int p = ss & 1;
    const bool more = (ss + 1 < 8);

    float wa[16], wb[16];
    float4 ua0 = {0,0,0,0}, ua1 = {0,0,0,0}, ub0 = {0,0,0,0}, ub1 = {0,0,0,0};
    if (more) {
      const float* sa = Wf + (size_t)(na + 2) * (D_IN * J) + t;
      const float* sb = Wf + (size_t)(na + 3) * (D_IN * J) + t;
      #pragma unroll
      for (int i = 0; i < 16; ++i) wa[i] = sa[i * J];
      #pragma unroll
      for (int i = 0; i < 16; ++i) wb[i] = sb[i * J];
      const float* upa = uf + ((size_t)b * N_IN + na + 2) * D_IN + kh * 8;
      ua0 = *reinterpret_cast<const float4*>(upa);
      ua1 = *reinterpret_cast<const float4*>(upa + 4);
      const float* upb = uf + ((size_t)b * N_IN + na + 3) * D_IN + kh * 8;
      ub0 = *reinterpret_cast<const float4*>(upb);
      ub1 = *reinterpret_cast<const float4*>(upb + 4);
      __builtin_amdgcn_sched_barrier(0);
    }

    // MFMA both n's, both tiles, in place
    {
      const uint4* bufA = Wt[2 * p];
      const uint4* bufB = Wt[2 * p + 1];
      #pragma unroll
      for (int q = 0; q < 2; ++q) {
        short8 A = *reinterpret_cast<const short8*>(&bufA[aoff[q]]);
        acc[q] = __builtin_amdgcn_mfma_f32_32x32x16_bf16(A, Ba, acc[q], 0, 0, 0);
      }
      #pragma unroll
      for (int q = 0; q < 2; ++q) {
        short8 A = *reinterpret_cast<const short8*>(&bufB[aoff[q]]);
        acc[q] = __builtin_amdgcn_mfma_f32_32x32x16_bf16(A, Bb, acc[q], 0, 0, 0);
      }
    }

    // write-late next pair
    short8 Bna, Bnb;
    if (more) {
      uint4 d0, d1;
      pack_col(wa, d0, d1);
      Wt[2 * (1 - p)][wp(2 * t)] = d0;
      Wt[2 * (1 - p)][wp(2 * t + 1)] = d1;
      if (wq) {
        uint4* g = reinterpret_cast<uint4*>(Wbf + (size_t)(na + 2) * (D_IN * J));
        g[wp(2 * t)] = d0;
        g[wp(2 * t + 1)] = d1;
      }
      pack_col(wb, d0, d1);
      Wt[2 * (1 - p) + 1][wp(2 * t)] = d0;
      Wt[2 * (1 - p) + 1][wp(2 * t + 1)] = d1;
      if (wq) {
        uint4* g = reinterpret_cast<uint4*>(Wbf + (size_t)(na + 3) * (D_IN * J));
        g[wp(2 * t)] = d0;
        g[wp(2 * t + 1)] = d1;
      }
      Bna = pack_u(ua0, ua1);
      Bnb = pack_u(ub0, ub1);
      if (uq) {
        *reinterpret_cast<short8*>(ubf + ((size_t)b * N_IN + na + 2) * D_IN + kh * 8) = Bna;
        *reinterpret_cast<short8*>(ubf + ((size_t)b * N_IN + na + 3) * D_IN + kh * 8) = Bnb;
      }
      Ba = Bna;
      Bb = Bnb;
    }
    __syncthreads();
  }

  // epilogue: part[cx][j][b]
  #pragma unroll
  for (int q = 0; q < 2; ++q) {
    #pragma unroll
    for (int r = 0; r < 16; ++r) {
      int j = w * 64 + q * 32 + (r & 3) + 8 * (r >> 2) + 4 * kh;
      part[((size_t)cx * J + j) * 64 + b] = acc[q][r];
    }
  }
}

// pass1w: routing pass (logits/softmax/scale) with 32x32x16, 32 b per block.
__global__ __launch_bounds__(1024, 1)
void pass1w_kernel(const short* __restrict__ Wbf, const short* __restrict__ ubf,
                   const float* __restrict__ vin, float* __restrict__ part)
{
  __shared__ uint4 Wt[2][2048];     // double-buffered (2 x 32KB)
  __shared__ float al[2][32][33];   // logits -> c, [parity][o][b_local]

  const int t  = threadIdx.x;
  const int l  = t & 63;
  const int w  = t >> 6;
  const int bid = blockIdx.x;
  const int bh = (bid >> 3) & 1;
  const int cx = (bid & 7) | ((bid >> 4) << 3);
  const int n0 = cx * 16;

  const int bl = l & 31;
  const int b  = bh * 32 + bl;
  const int kh = l >> 5;

  int aoff[2];
  #pragma unroll
  for (int q = 0; q < 2; ++q) aoff[q] = wp(2 * (w * 64 + q * 32 + bl) + kh);

  // v as packed bf16: vb[q*8 + 2g + d/2] holds rows 8g+4kh+{2d, 2d+1}
  unsigned vb[16];
  #pragma unroll
  for (int q = 0; q < 2; ++q) {
    #pragma unroll
    for (int g = 0; g < 4; ++g) {
      int j = w * 64 + q * 32 + 8 * g + 4 * kh;
      f32x4 v4 = *reinterpret_cast<const f32x4*>(vin + (size_t)b * J + j);
      vb[q * 8 + 2 * g]     = (unsigned)f2bf(v4[0]) | ((unsigned)f2bf(v4[1]) << 16);
      vb[q * 8 + 2 * g + 1] = (unsigned)f2bf(v4[2]) | ((unsigned)f2bf(v4[3]) << 16);
    }
  }

  f32x16 acc[2];
  acc[0] = zero16();
  acc[1] = zero16();

  short8 B;
  {
    const uint4* src = reinterpret_cast<const uint4*>(Wbf + (size_t)n0 * (D_IN * J));
    Wt[0][t] = src[t];
    Wt[0][t + 1024] = src[t + 1024];
    B = *reinterpret_cast<const short8*>(ubf + ((size_t)b * N_IN + n0) * D_IN + kh * 8);
  }
  __syncthreads();

  for (int nn = 0; nn < 16; ++nn) {
    const int n = n0 + nn;
    const int cur = nn & 1, nxt = cur ^ 1, par = nn & 1;
    const bool more = (nn + 1 < 16);

    // 1. prefetch next tile + next B
    uint4 s0, s1;
    short8 Bn;
    if (more) {
      const uint4* src = reinterpret_cast<const uint4*>(Wbf + (size_t)(n + 1) * (D_IN * J));
      s0 = src[t];
      s1 = src[t + 1024];
      Bn = *reinterpret_cast<const short8*>(ubf + ((size_t)b * N_IN + n + 1) * D_IN + kh * 8);
      __builtin_amdgcn_sched_barrier(0);
    }

    // 2. uhat: two 32x32 tiles
    f32x16 C[2];
    {
      const uint4* buf = Wt[cur];
      #pragma unroll
      for (int q = 0; q < 2; ++q) {
        short8 A = *reinterpret_cast<const short8*>(&buf[aoff[q]]);
        C[q] = __builtin_amdgcn_mfma_f32_32x32x16_bf16(A, B, zero16(), 0, 0, 0);
      }
    }

    // 3. agreement a[b][o]: sum lane's 16 rows * v, + khalf partner
    #pragma unroll
    for (int q = 0; q < 2; ++q) {
      float s = 0.f;
      #pragma unroll
      for (int r = 0; r < 16; ++r) {
        unsigned u = vb[q * 8 + (r >> 1)];
        float v = (r & 1) ? __uint_as_float(u & 0xffff0000u)
                          : __uint_as_float(u << 16);
        s += C[q][r] * v;
      }
      s += __shfl_xor(s, 32);
      if (l < 32) al[par][w * 2 + q][bl] = s;
    }

    // 4. write-late staging
    if (more) {
      Wt[nxt][t] = s0;
      Wt[nxt][t + 1024] = s1;
    }

    __syncthreads();   // (B) logits staged
    {
      // softmax over o: 1024 threads = 32 b x 32 o
      int sb = t >> 5, so = t & 31;
      float x = al[par][so][sb];
      float m = x;
      #pragma unroll
      for (int k = 1; k < 32; k <<= 1) m = fmaxf(m, __shfl_xor(m, k));
      float e = __expf(x - m);
      float sm = e;
      #pragma unroll
      for (int k = 1; k < 32; k <<= 1) sm += __shfl_xor(sm, k);
      al[par][so][sb] = e / sm;
    }
    __syncthreads();   // (C) c ready
    #pragma unroll
    for (int q = 0; q < 2; ++q) {
      float c = al[par][w * 2 + q][bl];
      #pragma unroll
      for (int r = 0; r < 16; ++r) acc[q][r] += C[q][r] * c;
    }
    // no end barrier: al parity-buffered; Wt hazards separated by (B)+(C)
    B = Bn;
  }

  // epilogue: part[cx][j][b]
  #pragma unroll
  for (int q = 0; q < 2; ++q) {
    #pragma unroll
    for (int r = 0; r < 16; ++r) {
      int j = w * 64 + q * 32 + (r & 3) + 8 * (r >> 2) + 4 * kh;
      part[((size_t)cx * J + j) * 64 + b] = acc[q][r];
    }
  }
}

// ============ old 16x16 pass_kernel (ws fallback only, MODE 2) ============
template<bool HAS_V, int MODE, int NCHUNK>
__global__ __launch_bounds__(1024, 1)
void pass_kernel(const float* __restrict__ uf, const float* __restrict__ Wf,
                 short* __restrict__ Wbf, short* __restrict__ ubf,
                 const float* __restrict__ vin, float* __restrict__ part)
{
  __shared__ uint4 Wt[2][2048];
  __shared__ float al[2][32][18];

  const int t  = threadIdx.x;
  const int l  = t & 63;
  const int w  = t >> 6;
  const int bid = blockIdx.x;
  const int bq = (bid >> 3) & 3;
  const int cx = (bid & 7) | ((bid >> 5) << 3);
  const int n0 = cx * NCHUNK;

  const int bl = l & 15;
  const int b  = bq * 16 + bl;
  const int h  = l >> 4;
  const int hA = h & 1;
  const bool ld = (l < 32);

  f32x4 vf[4];
  if (HAS_V) {
    #pragma unroll
    for (int q = 0; q < 4; ++q)
      vf[q] = *reinterpret_cast<const f32x4*>(vin + (size_t)b * J + (w*4+q)*16 + h*4);
  }

  int aoff[4];
  #pragma unroll
  for (int q = 0; q < 4; ++q) aoff[q] = wp(2 * ((w*4+q) * 16 + bl) + hA);

  f32x4 acc[4];
  #pragma unroll
  for (int q = 0; q < 4; ++q) acc[q] = f32x4{0.f, 0.f, 0.f, 0.f};

  short8 Bcur = short8{0,0,0,0,0,0,0,0};
  {
    float wc[16];
    const float* wsrc = Wf + (size_t)n0 * (D_IN * J) + t;
    #pragma unroll
    for (int i = 0; i < 16; ++i) wc[i] = wsrc[i * J];
    float4 a4 = {0,0,0,0}, b4 = {0,0,0,0};
    if (ld) {
      const float* up = uf + ((size_t)b * N_IN + n0) * D_IN + hA * 8;
      a4 = *reinterpret_cast<const float4*>(up);
      b4 = *reinterpret_cast<const float4*>(up + 4);
    }
    __builtin_amdgcn_sched_barrier(0);
    uint4 d0, d1;
    pack_col(wc, d0, d1);
    Wt[0][wp(2 * t)] = d0;
    Wt[0][wp(2 * t + 1)] = d1;
    if (ld) Bcur = pack_u(a4, b4);
  }
  __syncthreads();

  for (int nn = 0; nn < NCHUNK; ++nn) {
    const int n = n0 + nn;
    const int cur = nn & 1, nxt = cur ^ 1, par = nn & 1;
    const bool more = (nn + 1 < NCHUNK);

    float wc[16];
    float4 a4 = {0,0,0,0}, b4 = {0,0,0,0};
    if (more) {
      const float* wsrc = Wf + (size_t)(n + 1) * (D_IN * J) + t;
      #pragma unroll
      for (int i = 0; i < 16; ++i) wc[i] = wsrc[i * J];
      if (ld) {
        const float* up = uf + ((size_t)b * N_IN + n + 1) * D_IN + hA * 8;
        a4 = *reinterpret_cast<const float4*>(up);
        b4 = *reinterpret_cast<const float4*>(up + 4);
      }
      __builtin_amdgcn_sched_barrier(0);
    }

    f32x4 C[4];
    const uint4* buf = Wt[cur];
    #pragma unroll
    for (int q = 0; q < 4; ++q) {
      short8 A = short8{0,0,0,0,0,0,0,0};
      if (ld) A = *reinterpret_cast<const short8*>(&buf[aoff[q]]);
      f32x4 z = f32x4{0.f, 0.f, 0.f, 0.f};
      C[q] = __builtin_amdgcn_mfma_f32_16x16x32_bf16(A, Bcur, z, 0, 0, 0);
    }

    short8 Bn = short8{0,0,0,0,0,0,0,0};
    if (more && ld) Bn = pack_u(a4, b4);

    if (HAS_V) {
      float ap[2] = {0.f, 0.f};
      #pragma unroll
      for (int q = 0; q < 4; ++q) {
        float s = C[q][0]*vf[q][0] + C[q][1]*vf[q][1] + C[q][2]*vf[q][2] + C[q][3]*vf[q][3];
        ap[q >> 1] += s;
      }
      #pragma unroll
      for (int p = 0; p < 2; ++p) {
        float s = ap[p];
        s += __shfl_xor(s, 16);
        s += __shfl_xor(s, 32);
        if (l < 16) al[par][w * 2 + p][l] = s;
      }
      if (more) {
        uint4 d0, d1;
        pack_col(wc, d0, d1);
        Wt[nxt][wp(2 * t)] = d0;
        Wt[nxt][wp(2 * t + 1)] = d1;
      }
      __syncthreads();
      if (t < 512) {
        int sb = t >> 5, so = t & 31;
        float x = al[par][so][sb];
        float m = x;
        #pragma unroll
        for (int k = 1; k < 32; k <<= 1) m = fmaxf(m, __shfl_xor(m, k));
        float e = __expf(x - m);
        float sm = e;
        #pragma unroll
        for (int k = 1; k < 32; k <<= 1) sm += __shfl_xor(sm, k);
        al[par][so][sb] = e / sm;
      }
      __syncthreads();
      #pragma unroll
      for (int q = 0; q < 4; ++q) {
        float c = al[par][(w * 4 + q) >> 1][bl];
        acc[q] += C[q] * c;
      }
    } else {
      #pragma unroll
      for (int q = 0; q < 4; ++q) acc[q] += C[q];
      if (more) {
        uint4 d0, d1;
        pack_col(wc, d0, d1);
        Wt[nxt][wp(2 * t)] = d0;
        Wt[nxt][wp(2 * t + 1)] = d1;
      }
      __syncthreads();
    }
    Bcur = Bn;
  }

  #pragma unroll
  for (int q = 0; q < 4; ++q) {
    int jbase = (w * 4 + q) * 16 + h * 4;
    #pragma unroll
    for (int r = 0; r < 4; ++r)
      part[((size_t)cx * J + jbase + r) * 64 + b] = acc[q][r];
  }
}

// Fused chunk-reduce + squash. grid = 128 (o x b-quadrant), 1024 threads.
template<int NC>
__global__ __launch_bounds__(1024)
void rsq_kernel(const float* __restrict__ part, const float* __restrict__ addv,
                float* __restrict__ out, float prescale)
{
  __shared__ float ps[2][32][17];
  __shared__ float vl[32][17];
  __shared__ float scl[16];
  const int o  = blockIdx.x >> 2;
  const int bq = blockIdx.x & 3;
  const int t  = threadIdx.x;
  {
    const int bb = t & 15;
    const int kk = (t >> 4) & 31;
    const int ch = t >> 9;
    const float* p = part + (size_t)(o * 32 + kk) * 64 + bq * 16 + bb;
    float s = 0.f;
    #pragma unroll 8
    for (int c = ch * (NC / 2); c < (ch + 1) * (NC / 2); ++c)
      s += p[(size_t)c * (J * 64)];
    ps[ch][kk][bb] = s;
  }
  __syncthreads();
  if (t < 512) {
    int kk = t >> 4, bb = t & 15;
    vl[kk][bb] = (ps[0][kk][bb] + ps[1][kk][bb]) * prescale;
  }
  __syncthreads();
  if (t < 16) {
    float n2 = 0.f;
    #pragma unroll
    for (int k = 0; k < 32; ++k) { float x = vl[k][t]; n2 += x * x; }
    scl[t] = sqrtf(n2) / (1.f + n2);
  }
  __syncthreads();
  if (t < 512) {
    int bb = t >> 5, kk = t & 31;
    int idx = (bq * 16 + bb) * J + o * 32 + kk;
    float val = scl[bb] * vl[kk][bb];
    if (addv) val += addv[idx];
    out[idx] = val;
  }
}

extern "C" void kernel_launch(void* const* d_in, const int* in_sizes, int n_in,
                              void* d_out, int out_size, void* d_ws, size_t ws_size,
                              hipStream_t stream)
{
  const float* u = (const float*)d_in[0];
  const float* W = (const float*)d_in[1];
  float* out = (float*)d_out;
  char* ws = (char*)d_ws;

  const size_t WBF_B = (size_t)N_IN * D_IN * J * 2;        // 64 MB
  const size_t UBF_B = (size_t)BATCH * N_IN * D_IN * 2;    // 4 MB
  const size_t SMALL = 2ull * BATCH * J * 4;               // v0+vs
  const size_t PART128 = (size_t)128 * J * 64 * 4;         // 33.5 MB
  const size_t PART64  = (size_t)64 * J * 64 * 4;          // 16.7 MB

  if (ws_size >= WBF_B + UBF_B + PART128 + SMALL) {
    short* Wbf = (short*)ws;
    short* ubf = (short*)(ws + WBF_B);
    float* part = (float*)(ws + WBF_B + UBF_B);
    float* v0 = part + (size_t)128 * J * 64;
    float* vs = v0 + BATCH * J;
    // r=0: 32x32x16, paired-n, emits Wbf/ubf (each W tile read by 2 blocks not 4)
    pass0w_kernel<0><<<256, 1024, 0, stream>>>(u, W, Wbf, ubf, part);
    rsq_kernel<128><<<128, 1024, 0, stream>>>(part, nullptr, v0, 1.f / 32.f);
    // r=1,2: 32x32x16 routing passes
    pass1w_kernel<<<256, 1024, 0, stream>>>(Wbf, ubf, v0, part);
    rsq_kernel<128><<<128, 1024, 0, stream>>>(part, v0, vs, 1.f);
    pass1w_kernel<<<256, 1024, 0, stream>>>(Wbf, ubf, vs, part);
    rsq_kernel<128><<<128, 1024, 0, stream>>>(part, nullptr, out, 1.f);
  } else if (ws_size >= PART64 + SMALL) {
    float* part = (float*)ws;
    float* v0 = part + (size_t)64 * J * 64;
    float* vs = v0 + BATCH * J;
    pass_kernel<false, 2, 32><<<256, 1024, 0, stream>>>(u, W, nullptr, nullptr, nullptr, part);
    rsq_kernel<64><<<128, 1024, 0, stream>>>(part, nullptr, v0, 1.f / 32.f);
    pass_kernel<true, 2, 32><<<256, 1024, 0, stream>>>(u, W, nullptr, nullptr, v0, part);
    rsq_kernel<64><<<128, 1024, 0, stream>>>(part, v0, vs, 1.f);
    pass_kernel<true, 2, 32><<<256, 1024, 0, stream>>>(u, W, nullptr, nullptr, vs, part);
    rsq_kernel<64><<<128, 1024, 0, stream>>>(part, nullptr, out, 1.f);
  } else {
    float* part = (float*)ws;
    float* v0 = part + (size_t)16 * J * 64;
    float* vs = v0 + BATCH * J;
    pass_kernel<false, 2, 128><<<64, 1024, 0, stream>>>(u, W, nullptr, nullptr, nullptr, part);
    rsq_kernel<16><<<128, 1024, 0, stream>>>(part, nullptr, v0, 1.f / 32.f);
    pass_kernel<true, 2, 128><<<64, 1024, 0, stream>>>(u, W, nullptr, nullptr, v0, part);
    rsq_kernel<16><<<128, 1024, 0, stream>>>(part, v0, vs, 1.f);
    pass_kernel<true, 2, 128><<<64, 1024, 0, stream>>>(u, W, nullptr, nullptr, vs, part);
    rsq_kernel<16><<<128, 1024, 0, stream>>>(part, nullptr, out, 1.f);
  }
}